// Round 1
// baseline (1009.538 us; speedup 1.0000x reference)
//
#include <hip/hip_runtime.h>

#define N_NODES_C 50000
#define N_EDGES_C 800000
#define DIM 128
#define NCLS 40

// ---------------------------------------------------------------------------
// Frobenius-norm scales: block b reduces sum(W_b^2) over 128x128, writes 1/norm
__global__ __launch_bounds__(256) void k_scales(const float* __restrict__ W0,
                                                const float* __restrict__ W1,
                                                const float* __restrict__ W2,
                                                const float* __restrict__ W3,
                                                float* __restrict__ scale_inv) {
    const float* W = blockIdx.x == 0 ? W0 : blockIdx.x == 1 ? W1 : blockIdx.x == 2 ? W2 : W3;
    float s = 0.f;
    for (int i = threadIdx.x; i < DIM * DIM; i += 256) {
        float v = W[i];
        s += v * v;
    }
    #pragma unroll
    for (int off = 32; off >= 1; off >>= 1) s += __shfl_down(s, off);
    __shared__ float red[4];
    int lane = threadIdx.x & 63, wid = threadIdx.x >> 6;
    if (lane == 0) red[wid] = s;
    __syncthreads();
    if (threadIdx.x == 0) {
        float tot = red[0] + red[1] + red[2] + red[3];
        scale_inv[blockIdx.x] = 1.0f / sqrtf(tot);
    }
}

// ---------------------------------------------------------------------------
// in-degree histogram over dst
__global__ void k_deg(const int* __restrict__ A, int* __restrict__ cnt, int E) {
    int e = blockIdx.x * 256 + threadIdx.x;
    if (e >= E) return;
    atomicAdd(&cnt[A[E + e]], 1);
}

// single-block scan of counts -> csr_ptr, plus dinv = rsqrt(deg+1)
__global__ __launch_bounds__(1024) void k_scan(const int* __restrict__ cnt,
                                               int* __restrict__ ptr,
                                               float* __restrict__ dinv, int n) {
    __shared__ int wsum[16];
    __shared__ int wpre[16];
    __shared__ int sbase;
    int tid = threadIdx.x, lane = tid & 63, wid = tid >> 6;
    if (tid == 0) { sbase = 0; ptr[0] = 0; }
    __syncthreads();
    for (int start = 0; start < n; start += 1024) {
        int i = start + tid;
        int v = (i < n) ? cnt[i] : 0;
        if (i < n) dinv[i] = rsqrtf((float)v + 1.0f);
        int s = v;
        #pragma unroll
        for (int off = 1; off < 64; off <<= 1) {
            int t = __shfl_up(s, off);
            if (lane >= off) s += t;
        }
        if (lane == 63) wsum[wid] = s;
        __syncthreads();
        if (tid == 0) {
            int acc = sbase;
            #pragma unroll
            for (int w = 0; w < 16; ++w) { wpre[w] = acc; acc += wsum[w]; }
            sbase = acc;
        }
        __syncthreads();
        if (i < n) ptr[i + 1] = wpre[wid] + s;
        __syncthreads();
    }
}

// fill CSR: csrc[slot] = src, cw[slot] = dinv[src]
__global__ void k_fill(const int* __restrict__ A, const int* __restrict__ ptr,
                       int* __restrict__ fill, const float* __restrict__ dinv,
                       int* __restrict__ csrc, float* __restrict__ cw, int E) {
    int e = blockIdx.x * 256 + threadIdx.x;
    if (e >= E) return;
    int s = A[e];
    int d = A[E + e];
    int pos = ptr[d] + atomicAdd(&fill[d], 1);
    csrc[pos] = s;
    cw[pos] = dinv[s];
}

// ---------------------------------------------------------------------------
// fp32 GEMM: out[n][o] = scale * sum_k X[n][k] * W[o][k]   (K=128, O=128)
// 256 threads/block, 64 nodes/block; thread (tx,ty) owns 8 nodes x 4 outs.
__global__ __launch_bounds__(256) void k_gemm128(const float* __restrict__ X,
                                                 const float* __restrict__ W,
                                                 const float* __restrict__ scale_ptr,
                                                 float* __restrict__ out, int N) {
    __shared__ float Xs[16][68];    // [kk][node], padded to kill bank conflicts
    __shared__ float Ws[16][128];   // [kk][out]
    int tid = threadIdx.x;
    int n0 = blockIdx.x * 64;
    float scale = scale_ptr[0];
    int tx = tid & 31;   // out quad: outs tx*4 .. +3
    int ty = tid >> 5;   // node group: nodes ty*8 .. +7
    float acc[8][4] = {};
    for (int k0 = 0; k0 < DIM; k0 += 16) {
        {   // X tile: each thread one float4
            int j = tid >> 2, kq = tid & 3;
            int row = n0 + j;
            if (row >= N) row = N - 1;
            const float4 x4 = *reinterpret_cast<const float4*>(&X[(size_t)row * DIM + k0 + kq * 4]);
            Xs[kq * 4 + 0][j] = x4.x;
            Xs[kq * 4 + 1][j] = x4.y;
            Xs[kq * 4 + 2][j] = x4.z;
            Xs[kq * 4 + 3][j] = x4.w;
        }
        {   // W tile: each thread two float4 (8 k's of one out-row)
            int o = tid >> 1, kq = tid & 1;
            const float4 wa = *reinterpret_cast<const float4*>(&W[o * DIM + k0 + kq * 8]);
            const float4 wb = *reinterpret_cast<const float4*>(&W[o * DIM + k0 + kq * 8 + 4]);
            Ws[kq * 8 + 0][o] = wa.x;
            Ws[kq * 8 + 1][o] = wa.y;
            Ws[kq * 8 + 2][o] = wa.z;
            Ws[kq * 8 + 3][o] = wa.w;
            Ws[kq * 8 + 4][o] = wb.x;
            Ws[kq * 8 + 5][o] = wb.y;
            Ws[kq * 8 + 6][o] = wb.z;
            Ws[kq * 8 + 7][o] = wb.w;
        }
        __syncthreads();
        #pragma unroll
        for (int k = 0; k < 16; ++k) {
            float4 w = *reinterpret_cast<const float4*>(&Ws[k][tx * 4]);
            float4 xa = *reinterpret_cast<const float4*>(&Xs[k][ty * 8]);
            float4 xb = *reinterpret_cast<const float4*>(&Xs[k][ty * 8 + 4]);
            float xv[8] = {xa.x, xa.y, xa.z, xa.w, xb.x, xb.y, xb.z, xb.w};
            #pragma unroll
            for (int i = 0; i < 8; ++i) {
                acc[i][0] += xv[i] * w.x;
                acc[i][1] += xv[i] * w.y;
                acc[i][2] += xv[i] * w.z;
                acc[i][3] += xv[i] * w.w;
            }
        }
        __syncthreads();
    }
    #pragma unroll
    for (int i = 0; i < 8; ++i) {
        int row = n0 + ty * 8 + i;
        if (row < N) {
            float4 o4 = make_float4(acc[i][0] * scale, acc[i][1] * scale,
                                    acc[i][2] * scale, acc[i][3] * scale);
            *reinterpret_cast<float4*>(&out[(size_t)row * DIM + tx * 4]) = o4;
        }
    }
}

// ---------------------------------------------------------------------------
// aggregation + self-loop + bias (+ relu + residual). 2 nodes per 256-block.
__global__ __launch_bounds__(256) void k_agg(const float* __restrict__ G,
                                             const float* __restrict__ bias,
                                             const float* __restrict__ dinv,
                                             const int* __restrict__ ptr,
                                             const int* __restrict__ csrc,
                                             const float* __restrict__ cw,
                                             const float* __restrict__ skip,
                                             float* __restrict__ out,
                                             int relu_res, int N) {
    int n = blockIdx.x * 2 + (threadIdx.x >> 7);
    if (n >= N) return;
    int t = threadIdx.x & 127;
    int beg = ptr[n], end = ptr[n + 1];
    float acc = 0.f;
    for (int e = beg; e < end; ++e) {
        int s = csrc[e];
        acc += cw[e] * G[(size_t)s * DIM + t];
    }
    float di = dinv[n];
    float v = fmaf(di, acc, di * di * G[(size_t)n * DIM + t]) + bias[t];
    if (relu_res) v = fmaxf(v, 0.f) + skip[(size_t)n * DIM + t];
    out[(size_t)n * DIM + t] = v;
}

// ---------------------------------------------------------------------------
// final: out[n][o] = bf[o] + sum_k H[n][k] * Wf[o][k]   (O=40)
__global__ __launch_bounds__(256) void k_final(const float* __restrict__ H,
                                               const float* __restrict__ Wf,
                                               const float* __restrict__ bf,
                                               float* __restrict__ out, int N) {
    int idx = blockIdx.x * 256 + threadIdx.x;
    if (idx >= N * NCLS) return;
    int n = idx / NCLS;
    int o = idx - n * NCLS;
    const float4* hp = reinterpret_cast<const float4*>(&H[(size_t)n * DIM]);
    const float4* wp = reinterpret_cast<const float4*>(&Wf[(size_t)o * DIM]);
    float acc = 0.f;
    #pragma unroll
    for (int k = 0; k < DIM / 4; ++k) {
        float4 h4 = hp[k];
        float4 w4 = wp[k];
        acc += h4.x * w4.x + h4.y * w4.y + h4.z * w4.z + h4.w * w4.w;
    }
    out[idx] = acc + bf[o];
}

// ---------------------------------------------------------------------------
extern "C" void kernel_launch(void* const* d_in, const int* in_sizes, int n_in,
                              void* d_out, int out_size, void* d_ws, size_t ws_size,
                              hipStream_t stream) {
    (void)in_sizes; (void)n_in; (void)out_size; (void)ws_size;
    const float* X  = (const float*)d_in[0];
    const int*   A  = (const int*)d_in[1];
    const float* W0 = (const float*)d_in[2];
    const float* b0 = (const float*)d_in[3];
    const float* W1 = (const float*)d_in[4];
    const float* b1 = (const float*)d_in[5];
    const float* W2 = (const float*)d_in[6];
    const float* b2 = (const float*)d_in[7];
    const float* W3 = (const float*)d_in[8];
    const float* b3 = (const float*)d_in[9];
    const float* Wf = (const float*)d_in[10];
    const float* bf = (const float*)d_in[11];
    float* out = (float*)d_out;

    char* base = (char*)d_ws;
    size_t off = 0;
    auto alloc = [&](size_t bytes) -> char* {
        char* p = base + off;
        off = (off + bytes + 255) & ~(size_t)255;
        return p;
    };
    float* scale_inv = (float*)alloc(4 * sizeof(float));
    int*   deg   = (int*)alloc(N_NODES_C * sizeof(int));
    int*   fill  = (int*)alloc(N_NODES_C * sizeof(int));
    int*   ptr   = (int*)alloc((N_NODES_C + 1) * sizeof(int));
    float* dinv  = (float*)alloc(N_NODES_C * sizeof(float));
    int*   csrc  = (int*)alloc(N_EDGES_C * sizeof(int));
    float* cw    = (float*)alloc(N_EDGES_C * sizeof(float));
    float* G     = (float*)alloc((size_t)N_NODES_C * DIM * sizeof(float));
    float* H1    = (float*)alloc((size_t)N_NODES_C * DIM * sizeof(float));
    float* H2    = (float*)alloc((size_t)N_NODES_C * DIM * sizeof(float));

    hipMemsetAsync(deg, 0, N_NODES_C * sizeof(int), stream);
    hipMemsetAsync(fill, 0, N_NODES_C * sizeof(int), stream);

    k_scales<<<4, 256, 0, stream>>>(W0, W1, W2, W3, scale_inv);
    k_deg<<<(N_EDGES_C + 255) / 256, 256, 0, stream>>>(A, deg, N_EDGES_C);
    k_scan<<<1, 1024, 0, stream>>>(deg, ptr, dinv, N_NODES_C);
    k_fill<<<(N_EDGES_C + 255) / 256, 256, 0, stream>>>(A, ptr, fill, dinv, csrc, cw, N_EDGES_C);

    const int gemm_grid = (N_NODES_C + 63) / 64;
    const int agg_grid  = (N_NODES_C + 1) / 2;

    // layer 0
    k_gemm128<<<gemm_grid, 256, 0, stream>>>(X, W0, scale_inv + 0, G, N_NODES_C);
    k_agg<<<agg_grid, 256, 0, stream>>>(G, b0, dinv, ptr, csrc, cw, nullptr, H1, 0, N_NODES_C);
    // layer 1
    k_gemm128<<<gemm_grid, 256, 0, stream>>>(H1, W1, scale_inv + 1, G, N_NODES_C);
    k_agg<<<agg_grid, 256, 0, stream>>>(G, b1, dinv, ptr, csrc, cw, H1, H2, 1, N_NODES_C);
    // layer 2
    k_gemm128<<<gemm_grid, 256, 0, stream>>>(H2, W2, scale_inv + 2, G, N_NODES_C);
    k_agg<<<agg_grid, 256, 0, stream>>>(G, b2, dinv, ptr, csrc, cw, H2, H1, 1, N_NODES_C);
    // layer 3
    k_gemm128<<<gemm_grid, 256, 0, stream>>>(H1, W3, scale_inv + 3, G, N_NODES_C);
    k_agg<<<agg_grid, 256, 0, stream>>>(G, b3, dinv, ptr, csrc, cw, H1, H2, 1, N_NODES_C);
    // final classifier
    k_final<<<(N_NODES_C * NCLS + 255) / 256, 256, 0, stream>>>(H2, Wf, bf, out, N_NODES_C);
}

// Round 2
// 728.657 us; speedup vs baseline: 1.3855x; 1.3855x over previous
//
#include <hip/hip_runtime.h>

#define N_NODES_C 50000
#define N_EDGES_C 800000
#define DIM 128
#define NCLS 40

__device__ inline void fma4(float4& a, float w, const float4& g) {
    a.x = fmaf(w, g.x, a.x); a.y = fmaf(w, g.y, a.y);
    a.z = fmaf(w, g.z, a.z); a.w = fmaf(w, g.w, a.w);
}

// ---------------------------------------------------------------------------
// Frobenius-norm scales: block b reduces sum(W_b^2) over 128x128, writes 1/norm
__global__ __launch_bounds__(256) void k_scales(const float* __restrict__ W0,
                                                const float* __restrict__ W1,
                                                const float* __restrict__ W2,
                                                const float* __restrict__ W3,
                                                float* __restrict__ scale_inv) {
    const float* W = blockIdx.x == 0 ? W0 : blockIdx.x == 1 ? W1 : blockIdx.x == 2 ? W2 : W3;
    float s = 0.f;
    for (int i = threadIdx.x; i < DIM * DIM; i += 256) {
        float v = W[i];
        s += v * v;
    }
    #pragma unroll
    for (int off = 32; off >= 1; off >>= 1) s += __shfl_down(s, off);
    __shared__ float red[4];
    int lane = threadIdx.x & 63, wid = threadIdx.x >> 6;
    if (lane == 0) red[wid] = s;
    __syncthreads();
    if (threadIdx.x == 0) {
        float tot = red[0] + red[1] + red[2] + red[3];
        scale_inv[blockIdx.x] = 1.0f / sqrtf(tot);
    }
}

// ---------------------------------------------------------------------------
// in-degree histogram over dst
__global__ void k_deg(const int* __restrict__ A, int* __restrict__ cnt, int E) {
    int e = blockIdx.x * 256 + threadIdx.x;
    if (e >= E) return;
    atomicAdd(&cnt[A[E + e]], 1);
}

// one-pass scan: 1024 threads, each owns ceil(n/1024) contiguous nodes.
// writes exclusive prefix into ptr[0..n-1], total into ptr[n], dinv = rsqrt(deg+1)
__global__ __launch_bounds__(1024) void k_scan(const int* __restrict__ cnt,
                                               int* __restrict__ ptr,
                                               float* __restrict__ dinv, int n) {
    const int per = (n + 1023) / 1024;
    int tid = threadIdx.x;
    int base = tid * per;
    int s = 0;
    for (int i = 0; i < per; ++i) {
        int idx = base + i;
        if (idx < n) s += cnt[idx];
    }
    int lane = tid & 63, wid = tid >> 6;
    int sc = s;
    #pragma unroll
    for (int off = 1; off < 64; off <<= 1) {
        int t = __shfl_up(sc, off);
        if (lane >= off) sc += t;
    }
    __shared__ int wsum[16], wpre[16];
    if (lane == 63) wsum[wid] = sc;
    __syncthreads();
    if (tid == 0) {
        int acc = 0;
        #pragma unroll
        for (int w = 0; w < 16; ++w) { wpre[w] = acc; acc += wsum[w]; }
    }
    __syncthreads();
    int run = wpre[wid] + (sc - s);   // exclusive prefix for this thread's range
    for (int i = 0; i < per; ++i) {
        int idx = base + i;
        if (idx < n) {
            int v = cnt[idx];
            ptr[idx] = run;
            run += v;
            dinv[idx] = rsqrtf((float)v + 1.0f);
        }
    }
    if (tid == 1023) ptr[n] = run;    // thread 1023's range is past n -> run == total
}

// fill CSR: csrc[slot] = src, cw[slot] = dinv[src]
__global__ void k_fill(const int* __restrict__ A, const int* __restrict__ ptr,
                       int* __restrict__ fill, const float* __restrict__ dinv,
                       int* __restrict__ csrc, float* __restrict__ cw, int E) {
    int e = blockIdx.x * 256 + threadIdx.x;
    if (e >= E) return;
    int s = A[e];
    int d = A[E + e];
    int pos = ptr[d] + atomicAdd(&fill[d], 1);
    csrc[pos] = s;
    cw[pos] = dinv[s];
}

// ---------------------------------------------------------------------------
// fp32 GEMM: out[n][o] = scale * sum_k X[n][k] * W[o][k]   (K=128, O=128)
__global__ __launch_bounds__(256) void k_gemm128(const float* __restrict__ X,
                                                 const float* __restrict__ W,
                                                 const float* __restrict__ scale_ptr,
                                                 float* __restrict__ out, int N) {
    __shared__ float Xs[16][68];
    __shared__ float Ws[16][128];
    int tid = threadIdx.x;
    int n0 = blockIdx.x * 64;
    float scale = scale_ptr[0];
    int tx = tid & 31;
    int ty = tid >> 5;
    float acc[8][4] = {};
    for (int k0 = 0; k0 < DIM; k0 += 16) {
        {
            int j = tid >> 2, kq = tid & 3;
            int row = n0 + j;
            if (row >= N) row = N - 1;
            const float4 x4 = *reinterpret_cast<const float4*>(&X[(size_t)row * DIM + k0 + kq * 4]);
            Xs[kq * 4 + 0][j] = x4.x;
            Xs[kq * 4 + 1][j] = x4.y;
            Xs[kq * 4 + 2][j] = x4.z;
            Xs[kq * 4 + 3][j] = x4.w;
        }
        {
            int o = tid >> 1, kq = tid & 1;
            const float4 wa = *reinterpret_cast<const float4*>(&W[o * DIM + k0 + kq * 8]);
            const float4 wb = *reinterpret_cast<const float4*>(&W[o * DIM + k0 + kq * 8 + 4]);
            Ws[kq * 8 + 0][o] = wa.x;
            Ws[kq * 8 + 1][o] = wa.y;
            Ws[kq * 8 + 2][o] = wa.z;
            Ws[kq * 8 + 3][o] = wa.w;
            Ws[kq * 8 + 4][o] = wb.x;
            Ws[kq * 8 + 5][o] = wb.y;
            Ws[kq * 8 + 6][o] = wb.z;
            Ws[kq * 8 + 7][o] = wb.w;
        }
        __syncthreads();
        #pragma unroll
        for (int k = 0; k < 16; ++k) {
            float4 w = *reinterpret_cast<const float4*>(&Ws[k][tx * 4]);
            float4 xa = *reinterpret_cast<const float4*>(&Xs[k][ty * 8]);
            float4 xb = *reinterpret_cast<const float4*>(&Xs[k][ty * 8 + 4]);
            float xv[8] = {xa.x, xa.y, xa.z, xa.w, xb.x, xb.y, xb.z, xb.w};
            #pragma unroll
            for (int i = 0; i < 8; ++i) {
                acc[i][0] += xv[i] * w.x;
                acc[i][1] += xv[i] * w.y;
                acc[i][2] += xv[i] * w.z;
                acc[i][3] += xv[i] * w.w;
            }
        }
        __syncthreads();
    }
    #pragma unroll
    for (int i = 0; i < 8; ++i) {
        int row = n0 + ty * 8 + i;
        if (row < N) {
            float4 o4 = make_float4(acc[i][0] * scale, acc[i][1] * scale,
                                    acc[i][2] * scale, acc[i][3] * scale);
            *reinterpret_cast<float4*>(&out[(size_t)row * DIM + tx * 4]) = o4;
        }
    }
}

// ---------------------------------------------------------------------------
// aggregation + self-loop + bias (+ relu + residual).
// 8 nodes per 256-block; 32 lanes per node; float4 per lane; edge loop
// unrolled x4 with 4 independent accumulators (4 outstanding 16B gathers).
__global__ __launch_bounds__(256) void k_agg(const float* __restrict__ G,
                                             const float* __restrict__ bias,
                                             const float* __restrict__ dinv,
                                             const int* __restrict__ ptr,
                                             const int* __restrict__ csrc,
                                             const float* __restrict__ cw,
                                             const float* __restrict__ skip,
                                             float* __restrict__ out,
                                             int relu_res, int N) {
    int n = blockIdx.x * 8 + (threadIdx.x >> 5);
    if (n >= N) return;
    int l = threadIdx.x & 31;
    const float4* __restrict__ Gv = reinterpret_cast<const float4*>(G);
    int beg = ptr[n], end = ptr[n + 1];
    float4 a0 = make_float4(0.f, 0.f, 0.f, 0.f), a1 = a0, a2 = a0, a3 = a0;
    int e = beg;
    for (; e + 4 <= end; e += 4) {
        int s0 = csrc[e + 0], s1 = csrc[e + 1], s2 = csrc[e + 2], s3 = csrc[e + 3];
        float w0 = cw[e + 0], w1 = cw[e + 1], w2 = cw[e + 2], w3 = cw[e + 3];
        float4 g0 = Gv[(size_t)s0 * 32 + l];
        float4 g1 = Gv[(size_t)s1 * 32 + l];
        float4 g2 = Gv[(size_t)s2 * 32 + l];
        float4 g3 = Gv[(size_t)s3 * 32 + l];
        fma4(a0, w0, g0);
        fma4(a1, w1, g1);
        fma4(a2, w2, g2);
        fma4(a3, w3, g3);
    }
    for (; e < end; ++e) {
        int s = csrc[e];
        float w = cw[e];
        float4 g = Gv[(size_t)s * 32 + l];
        fma4(a0, w, g);
    }
    float4 acc;
    acc.x = (a0.x + a1.x) + (a2.x + a3.x);
    acc.y = (a0.y + a1.y) + (a2.y + a3.y);
    acc.z = (a0.z + a1.z) + (a2.z + a3.z);
    acc.w = (a0.w + a1.w) + (a2.w + a3.w);

    float di = dinv[n];
    float d2 = di * di;
    float4 gs = Gv[(size_t)n * 32 + l];
    float4 b4 = reinterpret_cast<const float4*>(bias)[l];
    float4 v;
    v.x = fmaf(di, acc.x, fmaf(d2, gs.x, b4.x));
    v.y = fmaf(di, acc.y, fmaf(d2, gs.y, b4.y));
    v.z = fmaf(di, acc.z, fmaf(d2, gs.z, b4.z));
    v.w = fmaf(di, acc.w, fmaf(d2, gs.w, b4.w));
    if (relu_res) {
        float4 s4 = reinterpret_cast<const float4*>(skip)[(size_t)n * 32 + l];
        v.x = fmaxf(v.x, 0.f) + s4.x;
        v.y = fmaxf(v.y, 0.f) + s4.y;
        v.z = fmaxf(v.z, 0.f) + s4.z;
        v.w = fmaxf(v.w, 0.f) + s4.w;
    }
    reinterpret_cast<float4*>(out)[(size_t)n * 32 + l] = v;
}

// ---------------------------------------------------------------------------
// final: out[n][o] = bf[o] + sum_k H[n][k] * Wf[o][k]   (O=40)
__global__ __launch_bounds__(256) void k_final(const float* __restrict__ H,
                                               const float* __restrict__ Wf,
                                               const float* __restrict__ bf,
                                               float* __restrict__ out, int N) {
    int idx = blockIdx.x * 256 + threadIdx.x;
    if (idx >= N * NCLS) return;
    int n = idx / NCLS;
    int o = idx - n * NCLS;
    const float4* hp = reinterpret_cast<const float4*>(&H[(size_t)n * DIM]);
    const float4* wp = reinterpret_cast<const float4*>(&Wf[(size_t)o * DIM]);
    float acc = 0.f;
    #pragma unroll
    for (int k = 0; k < DIM / 4; ++k) {
        float4 h4 = hp[k];
        float4 w4 = wp[k];
        acc += h4.x * w4.x + h4.y * w4.y + h4.z * w4.z + h4.w * w4.w;
    }
    out[idx] = acc + bf[o];
}

// ---------------------------------------------------------------------------
extern "C" void kernel_launch(void* const* d_in, const int* in_sizes, int n_in,
                              void* d_out, int out_size, void* d_ws, size_t ws_size,
                              hipStream_t stream) {
    (void)in_sizes; (void)n_in; (void)out_size; (void)ws_size;
    const float* X  = (const float*)d_in[0];
    const int*   A  = (const int*)d_in[1];
    const float* W0 = (const float*)d_in[2];
    const float* b0 = (const float*)d_in[3];
    const float* W1 = (const float*)d_in[4];
    const float* b1 = (const float*)d_in[5];
    const float* W2 = (const float*)d_in[6];
    const float* b2 = (const float*)d_in[7];
    const float* W3 = (const float*)d_in[8];
    const float* b3 = (const float*)d_in[9];
    const float* Wf = (const float*)d_in[10];
    const float* bf = (const float*)d_in[11];
    float* out = (float*)d_out;

    char* base = (char*)d_ws;
    size_t off = 0;
    auto alloc = [&](size_t bytes) -> char* {
        char* p = base + off;
        off = (off + bytes + 255) & ~(size_t)255;
        return p;
    };
    float* scale_inv = (float*)alloc(4 * sizeof(float));
    int*   deg   = (int*)alloc(N_NODES_C * sizeof(int));
    int*   fill  = (int*)alloc(N_NODES_C * sizeof(int));
    int*   ptr   = (int*)alloc((N_NODES_C + 1) * sizeof(int));
    float* dinv  = (float*)alloc(N_NODES_C * sizeof(float));
    int*   csrc  = (int*)alloc(N_EDGES_C * sizeof(int));
    float* cw    = (float*)alloc(N_EDGES_C * sizeof(float));
    float* G     = (float*)alloc((size_t)N_NODES_C * DIM * sizeof(float));
    float* H1    = (float*)alloc((size_t)N_NODES_C * DIM * sizeof(float));
    float* H2    = (float*)alloc((size_t)N_NODES_C * DIM * sizeof(float));

    hipMemsetAsync(deg, 0, N_NODES_C * sizeof(int), stream);
    hipMemsetAsync(fill, 0, N_NODES_C * sizeof(int), stream);

    k_scales<<<4, 256, 0, stream>>>(W0, W1, W2, W3, scale_inv);
    k_deg<<<(N_EDGES_C + 255) / 256, 256, 0, stream>>>(A, deg, N_EDGES_C);
    k_scan<<<1, 1024, 0, stream>>>(deg, ptr, dinv, N_NODES_C);
    k_fill<<<(N_EDGES_C + 255) / 256, 256, 0, stream>>>(A, ptr, fill, dinv, csrc, cw, N_EDGES_C);

    const int gemm_grid = (N_NODES_C + 63) / 64;
    const int agg_grid  = (N_NODES_C + 7) / 8;

    // layer 0
    k_gemm128<<<gemm_grid, 256, 0, stream>>>(X, W0, scale_inv + 0, G, N_NODES_C);
    k_agg<<<agg_grid, 256, 0, stream>>>(G, b0, dinv, ptr, csrc, cw, nullptr, H1, 0, N_NODES_C);
    // layer 1
    k_gemm128<<<gemm_grid, 256, 0, stream>>>(H1, W1, scale_inv + 1, G, N_NODES_C);
    k_agg<<<agg_grid, 256, 0, stream>>>(G, b1, dinv, ptr, csrc, cw, H1, H2, 1, N_NODES_C);
    // layer 2
    k_gemm128<<<gemm_grid, 256, 0, stream>>>(H2, W2, scale_inv + 2, G, N_NODES_C);
    k_agg<<<agg_grid, 256, 0, stream>>>(G, b2, dinv, ptr, csrc, cw, H2, H1, 1, N_NODES_C);
    // layer 3
    k_gemm128<<<gemm_grid, 256, 0, stream>>>(H1, W3, scale_inv + 3, G, N_NODES_C);
    k_agg<<<agg_grid, 256, 0, stream>>>(G, b3, dinv, ptr, csrc, cw, H1, H2, 1, N_NODES_C);
    // final classifier
    k_final<<<(N_NODES_C * NCLS + 255) / 256, 256, 0, stream>>>(H2, Wf, bf, out, N_NODES_C);
}

// Round 3
// 611.960 us; speedup vs baseline: 1.6497x; 1.1907x over previous
//
#include <hip/hip_runtime.h>

#define N_NODES_C 50000
#define N_EDGES_C 800000
#define DIM 128
#define NCLS 40

__device__ inline void fma4(float4& a, float w, const float4& g) {
    a.x = fmaf(w, g.x, a.x); a.y = fmaf(w, g.y, a.y);
    a.z = fmaf(w, g.z, a.z); a.w = fmaf(w, g.w, a.w);
}

// ---------------------------------------------------------------------------
// Frobenius-norm scales: block b reduces sum(W_b^2) over 128x128, writes 1/norm
__global__ __launch_bounds__(256) void k_scales(const float* __restrict__ W0,
                                                const float* __restrict__ W1,
                                                const float* __restrict__ W2,
                                                const float* __restrict__ W3,
                                                float* __restrict__ scale_inv) {
    const float* W = blockIdx.x == 0 ? W0 : blockIdx.x == 1 ? W1 : blockIdx.x == 2 ? W2 : W3;
    float s = 0.f;
    for (int i = threadIdx.x; i < DIM * DIM; i += 256) {
        float v = W[i];
        s += v * v;
    }
    #pragma unroll
    for (int off = 32; off >= 1; off >>= 1) s += __shfl_down(s, off);
    __shared__ float red[4];
    int lane = threadIdx.x & 63, wid = threadIdx.x >> 6;
    if (lane == 0) red[wid] = s;
    __syncthreads();
    if (threadIdx.x == 0) {
        float tot = red[0] + red[1] + red[2] + red[3];
        scale_inv[blockIdx.x] = 1.0f / sqrtf(tot);
    }
}

// ---------------------------------------------------------------------------
// in-degree histogram over dst
__global__ void k_deg(const int* __restrict__ A, int* __restrict__ cnt, int E) {
    int e = blockIdx.x * 256 + threadIdx.x;
    if (e >= E) return;
    atomicAdd(&cnt[A[E + e]], 1);
}

// one-pass scan: 1024 threads, each owns ceil(n/1024) contiguous nodes.
__global__ __launch_bounds__(1024) void k_scan(const int* __restrict__ cnt,
                                               int* __restrict__ ptr,
                                               float* __restrict__ dinv, int n) {
    const int per = (n + 1023) / 1024;
    int tid = threadIdx.x;
    int base = tid * per;
    int s = 0;
    for (int i = 0; i < per; ++i) {
        int idx = base + i;
        if (idx < n) s += cnt[idx];
    }
    int lane = tid & 63, wid = tid >> 6;
    int sc = s;
    #pragma unroll
    for (int off = 1; off < 64; off <<= 1) {
        int t = __shfl_up(sc, off);
        if (lane >= off) sc += t;
    }
    __shared__ int wsum[16], wpre[16];
    if (lane == 63) wsum[wid] = sc;
    __syncthreads();
    if (tid == 0) {
        int acc = 0;
        #pragma unroll
        for (int w = 0; w < 16; ++w) { wpre[w] = acc; acc += wsum[w]; }
    }
    __syncthreads();
    int run = wpre[wid] + (sc - s);
    for (int i = 0; i < per; ++i) {
        int idx = base + i;
        if (idx < n) {
            int v = cnt[idx];
            ptr[idx] = run;
            run += v;
            dinv[idx] = rsqrtf((float)v + 1.0f);
        }
    }
    if (tid == 1023) ptr[n] = run;
}

// fill CSR: csrc[slot] = src, cw[slot] = dinv[src]
__global__ void k_fill(const int* __restrict__ A, const int* __restrict__ ptr,
                       int* __restrict__ fill, const float* __restrict__ dinv,
                       int* __restrict__ csrc, float* __restrict__ cw, int E) {
    int e = blockIdx.x * 256 + threadIdx.x;
    if (e >= E) return;
    int s = A[e];
    int d = A[E + e];
    int pos = ptr[d] + atomicAdd(&fill[d], 1);
    csrc[pos] = s;
    cw[pos] = dinv[s];
}

// ---------------------------------------------------------------------------
// fp32 GEMM: out[n][o] = scale * sum_k X[n][k] * W[o][k]   (K=128, O=128)
__global__ __launch_bounds__(256) void k_gemm128(const float* __restrict__ X,
                                                 const float* __restrict__ W,
                                                 const float* __restrict__ scale_ptr,
                                                 float* __restrict__ out, int N) {
    __shared__ float Xs[16][68];
    __shared__ float Ws[16][128];
    int tid = threadIdx.x;
    int n0 = blockIdx.x * 64;
    float scale = scale_ptr[0];
    int tx = tid & 31;
    int ty = tid >> 5;
    float acc[8][4] = {};
    for (int k0 = 0; k0 < DIM; k0 += 16) {
        {
            int j = tid >> 2, kq = tid & 3;
            int row = n0 + j;
            if (row >= N) row = N - 1;
            const float4 x4 = *reinterpret_cast<const float4*>(&X[(size_t)row * DIM + k0 + kq * 4]);
            Xs[kq * 4 + 0][j] = x4.x;
            Xs[kq * 4 + 1][j] = x4.y;
            Xs[kq * 4 + 2][j] = x4.z;
            Xs[kq * 4 + 3][j] = x4.w;
        }
        {
            int o = tid >> 1, kq = tid & 1;
            const float4 wa = *reinterpret_cast<const float4*>(&W[o * DIM + k0 + kq * 8]);
            const float4 wb = *reinterpret_cast<const float4*>(&W[o * DIM + k0 + kq * 8 + 4]);
            Ws[kq * 8 + 0][o] = wa.x;
            Ws[kq * 8 + 1][o] = wa.y;
            Ws[kq * 8 + 2][o] = wa.z;
            Ws[kq * 8 + 3][o] = wa.w;
            Ws[kq * 8 + 4][o] = wb.x;
            Ws[kq * 8 + 5][o] = wb.y;
            Ws[kq * 8 + 6][o] = wb.z;
            Ws[kq * 8 + 7][o] = wb.w;
        }
        __syncthreads();
        #pragma unroll
        for (int k = 0; k < 16; ++k) {
            float4 w = *reinterpret_cast<const float4*>(&Ws[k][tx * 4]);
            float4 xa = *reinterpret_cast<const float4*>(&Xs[k][ty * 8]);
            float4 xb = *reinterpret_cast<const float4*>(&Xs[k][ty * 8 + 4]);
            float xv[8] = {xa.x, xa.y, xa.z, xa.w, xb.x, xb.y, xb.z, xb.w};
            #pragma unroll
            for (int i = 0; i < 8; ++i) {
                acc[i][0] += xv[i] * w.x;
                acc[i][1] += xv[i] * w.y;
                acc[i][2] += xv[i] * w.z;
                acc[i][3] += xv[i] * w.w;
            }
        }
        __syncthreads();
    }
    #pragma unroll
    for (int i = 0; i < 8; ++i) {
        int row = n0 + ty * 8 + i;
        if (row < N) {
            float4 o4 = make_float4(acc[i][0] * scale, acc[i][1] * scale,
                                    acc[i][2] * scale, acc[i][3] * scale);
            *reinterpret_cast<float4*>(&out[(size_t)row * DIM + tx * 4]) = o4;
        }
    }
}

// ---------------------------------------------------------------------------
// aggregation + self-loop + bias (+ relu + residual).
// 8 nodes per 256-block; 32 lanes per node; float4 per lane; 4-deep unroll.
__global__ __launch_bounds__(256) void k_agg(const float* __restrict__ G,
                                             const float* __restrict__ bias,
                                             const float* __restrict__ dinv,
                                             const int* __restrict__ ptr,
                                             const int* __restrict__ csrc,
                                             const float* __restrict__ cw,
                                             const float* __restrict__ skip,
                                             float* __restrict__ out,
                                             int relu_res, int N) {
    int n = blockIdx.x * 8 + (threadIdx.x >> 5);
    if (n >= N) return;
    int l = threadIdx.x & 31;
    const float4* __restrict__ Gv = reinterpret_cast<const float4*>(G);
    int beg = ptr[n], end = ptr[n + 1];
    float4 a0 = make_float4(0.f, 0.f, 0.f, 0.f), a1 = a0, a2 = a0, a3 = a0;
    int e = beg;
    for (; e + 4 <= end; e += 4) {
        int s0 = csrc[e + 0], s1 = csrc[e + 1], s2 = csrc[e + 2], s3 = csrc[e + 3];
        float w0 = cw[e + 0], w1 = cw[e + 1], w2 = cw[e + 2], w3 = cw[e + 3];
        float4 g0 = Gv[(size_t)s0 * 32 + l];
        float4 g1 = Gv[(size_t)s1 * 32 + l];
        float4 g2 = Gv[(size_t)s2 * 32 + l];
        float4 g3 = Gv[(size_t)s3 * 32 + l];
        fma4(a0, w0, g0);
        fma4(a1, w1, g1);
        fma4(a2, w2, g2);
        fma4(a3, w3, g3);
    }
    for (; e < end; ++e) {
        int s = csrc[e];
        float w = cw[e];
        float4 g = Gv[(size_t)s * 32 + l];
        fma4(a0, w, g);
    }
    float4 acc;
    acc.x = (a0.x + a1.x) + (a2.x + a3.x);
    acc.y = (a0.y + a1.y) + (a2.y + a3.y);
    acc.z = (a0.z + a1.z) + (a2.z + a3.z);
    acc.w = (a0.w + a1.w) + (a2.w + a3.w);

    float di = dinv[n];
    float d2 = di * di;
    float4 gs = Gv[(size_t)n * 32 + l];
    float4 b4 = reinterpret_cast<const float4*>(bias)[l];
    float4 v;
    v.x = fmaf(di, acc.x, fmaf(d2, gs.x, b4.x));
    v.y = fmaf(di, acc.y, fmaf(d2, gs.y, b4.y));
    v.z = fmaf(di, acc.z, fmaf(d2, gs.z, b4.z));
    v.w = fmaf(di, acc.w, fmaf(d2, gs.w, b4.w));
    if (relu_res) {
        float4 s4 = reinterpret_cast<const float4*>(skip)[(size_t)n * 32 + l];
        v.x = fmaxf(v.x, 0.f) + s4.x;
        v.y = fmaxf(v.y, 0.f) + s4.y;
        v.z = fmaxf(v.z, 0.f) + s4.z;
        v.w = fmaxf(v.w, 0.f) + s4.w;
    }
    reinterpret_cast<float4*>(out)[(size_t)n * 32 + l] = v;
}

// ---------------------------------------------------------------------------
// final classifier as LDS-tiled GEMM: out[n][o] = bf[o] + sum_k H[n][k]*Wf[o][k]
// 64 nodes x 64 outs (outs padded 40->64) per 256-thread block; 4x4 per thread.
__global__ __launch_bounds__(256) void k_final(const float* __restrict__ H,
                                               const float* __restrict__ Wf,
                                               const float* __restrict__ bf,
                                               float* __restrict__ out, int N) {
    __shared__ float Xs[16][68];   // [k][node]
    __shared__ float Ws[16][64];   // [k][out(padded)]
    int tid = threadIdx.x;
    int n0 = blockIdx.x * 64;
    int tx = tid & 15;   // out quad: outs tx*4 .. +3
    int ty = tid >> 4;   // node quad: nodes ty*4 .. +3
    float acc[4][4] = {};
    for (int k0 = 0; k0 < DIM; k0 += 16) {
        {   // X tile: thread -> node j, k-quad kq
            int j = tid >> 2, kq = tid & 3;
            int row = n0 + j;
            if (row >= N) row = N - 1;
            const float4 x4 = *reinterpret_cast<const float4*>(&H[(size_t)row * DIM + k0 + kq * 4]);
            Xs[kq * 4 + 0][j] = x4.x;
            Xs[kq * 4 + 1][j] = x4.y;
            Xs[kq * 4 + 2][j] = x4.z;
            Xs[kq * 4 + 3][j] = x4.w;
        }
        {   // W tile: thread -> out o (clamped to 40 rows), k-quad kq
            int o = tid >> 2, kq = tid & 3;
            int om = o < NCLS ? o : o - NCLS;   // pad rows repeat first 24
            const float4 w4 = *reinterpret_cast<const float4*>(&Wf[(size_t)om * DIM + k0 + kq * 4]);
            Ws[kq * 4 + 0][o] = w4.x;
            Ws[kq * 4 + 1][o] = w4.y;
            Ws[kq * 4 + 2][o] = w4.z;
            Ws[kq * 4 + 3][o] = w4.w;
        }
        __syncthreads();
        #pragma unroll
        for (int k = 0; k < 16; ++k) {
            float4 w = *reinterpret_cast<const float4*>(&Ws[k][tx * 4]);
            float4 x = *reinterpret_cast<const float4*>(&Xs[k][ty * 4]);
            float xv[4] = {x.x, x.y, x.z, x.w};
            #pragma unroll
            for (int i = 0; i < 4; ++i) {
                acc[i][0] = fmaf(xv[i], w.x, acc[i][0]);
                acc[i][1] = fmaf(xv[i], w.y, acc[i][1]);
                acc[i][2] = fmaf(xv[i], w.z, acc[i][2]);
                acc[i][3] = fmaf(xv[i], w.w, acc[i][3]);
            }
        }
        __syncthreads();
    }
    if (tx >= 10) return;   // outs 40..63 are padding
    float4 b4 = make_float4(bf[tx * 4], bf[tx * 4 + 1], bf[tx * 4 + 2], bf[tx * 4 + 3]);
    #pragma unroll
    for (int i = 0; i < 4; ++i) {
        int row = n0 + ty * 4 + i;
        if (row < N) {
            float* op = &out[(size_t)row * NCLS + tx * 4];
            op[0] = acc[i][0] + b4.x;
            op[1] = acc[i][1] + b4.y;
            op[2] = acc[i][2] + b4.z;
            op[3] = acc[i][3] + b4.w;
        }
    }
}

// ---------------------------------------------------------------------------
extern "C" void kernel_launch(void* const* d_in, const int* in_sizes, int n_in,
                              void* d_out, int out_size, void* d_ws, size_t ws_size,
                              hipStream_t stream) {
    (void)in_sizes; (void)n_in; (void)out_size; (void)ws_size;
    const float* X  = (const float*)d_in[0];
    const int*   A  = (const int*)d_in[1];
    const float* W0 = (const float*)d_in[2];
    const float* b0 = (const float*)d_in[3];
    const float* W1 = (const float*)d_in[4];
    const float* b1 = (const float*)d_in[5];
    const float* W2 = (const float*)d_in[6];
    const float* b2 = (const float*)d_in[7];
    const float* W3 = (const float*)d_in[8];
    const float* b3 = (const float*)d_in[9];
    const float* Wf = (const float*)d_in[10];
    const float* bf = (const float*)d_in[11];
    float* out = (float*)d_out;

    char* base = (char*)d_ws;
    size_t off = 0;
    auto alloc = [&](size_t bytes) -> char* {
        char* p = base + off;
        off = (off + bytes + 255) & ~(size_t)255;
        return p;
    };
    float* scale_inv = (float*)alloc(4 * sizeof(float));
    int*   deg   = (int*)alloc(N_NODES_C * sizeof(int));
    int*   fill  = (int*)alloc(N_NODES_C * sizeof(int));
    int*   ptr   = (int*)alloc((N_NODES_C + 1) * sizeof(int));
    float* dinv  = (float*)alloc(N_NODES_C * sizeof(float));
    int*   csrc  = (int*)alloc(N_EDGES_C * sizeof(int));
    float* cw    = (float*)alloc(N_EDGES_C * sizeof(float));
    float* G     = (float*)alloc((size_t)N_NODES_C * DIM * sizeof(float));
    float* H1    = (float*)alloc((size_t)N_NODES_C * DIM * sizeof(float));
    float* H2    = (float*)alloc((size_t)N_NODES_C * DIM * sizeof(float));

    hipMemsetAsync(deg, 0, N_NODES_C * sizeof(int), stream);
    hipMemsetAsync(fill, 0, N_NODES_C * sizeof(int), stream);

    k_scales<<<4, 256, 0, stream>>>(W0, W1, W2, W3, scale_inv);
    k_deg<<<(N_EDGES_C + 255) / 256, 256, 0, stream>>>(A, deg, N_EDGES_C);
    k_scan<<<1, 1024, 0, stream>>>(deg, ptr, dinv, N_NODES_C);
    k_fill<<<(N_EDGES_C + 255) / 256, 256, 0, stream>>>(A, ptr, fill, dinv, csrc, cw, N_EDGES_C);

    const int gemm_grid = (N_NODES_C + 63) / 64;
    const int agg_grid  = (N_NODES_C + 7) / 8;

    // layer 0
    k_gemm128<<<gemm_grid, 256, 0, stream>>>(X, W0, scale_inv + 0, G, N_NODES_C);
    k_agg<<<agg_grid, 256, 0, stream>>>(G, b0, dinv, ptr, csrc, cw, nullptr, H1, 0, N_NODES_C);
    // layer 1
    k_gemm128<<<gemm_grid, 256, 0, stream>>>(H1, W1, scale_inv + 1, G, N_NODES_C);
    k_agg<<<agg_grid, 256, 0, stream>>>(G, b1, dinv, ptr, csrc, cw, H1, H2, 1, N_NODES_C);
    // layer 2
    k_gemm128<<<gemm_grid, 256, 0, stream>>>(H2, W2, scale_inv + 2, G, N_NODES_C);
    k_agg<<<agg_grid, 256, 0, stream>>>(G, b2, dinv, ptr, csrc, cw, H2, H1, 1, N_NODES_C);
    // layer 3
    k_gemm128<<<gemm_grid, 256, 0, stream>>>(H1, W3, scale_inv + 3, G, N_NODES_C);
    k_agg<<<agg_grid, 256, 0, stream>>>(G, b3, dinv, ptr, csrc, cw, H1, H2, 1, N_NODES_C);
    // final classifier
    k_final<<<(N_NODES_C + 63) / 64, 256, 0, stream>>>(H2, Wf, bf, out, N_NODES_C);
}

// Round 4
// 518.125 us; speedup vs baseline: 1.9484x; 1.1811x over previous
//
#include <hip/hip_runtime.h>

#define N_NODES_C 50000
#define N_EDGES_C 800000
#define DIM 128
#define NCLS 40
#define SCAN_NB ((N_NODES_C + 255) / 256)

__device__ inline void fma4(float4& a, float w, const float4& g) {
    a.x = fmaf(w, g.x, a.x); a.y = fmaf(w, g.y, a.y);
    a.z = fmaf(w, g.z, a.z); a.w = fmaf(w, g.w, a.w);
}

// ---------------------------------------------------------------------------
// Frobenius-norm scales
__global__ __launch_bounds__(256) void k_scales(const float* __restrict__ W0,
                                                const float* __restrict__ W1,
                                                const float* __restrict__ W2,
                                                const float* __restrict__ W3,
                                                float* __restrict__ scale_inv) {
    const float* W = blockIdx.x == 0 ? W0 : blockIdx.x == 1 ? W1 : blockIdx.x == 2 ? W2 : W3;
    float s = 0.f;
    for (int i = threadIdx.x; i < DIM * DIM; i += 256) {
        float v = W[i];
        s += v * v;
    }
    #pragma unroll
    for (int off = 32; off >= 1; off >>= 1) s += __shfl_down(s, off);
    __shared__ float red[4];
    int lane = threadIdx.x & 63, wid = threadIdx.x >> 6;
    if (lane == 0) red[wid] = s;
    __syncthreads();
    if (threadIdx.x == 0) {
        float tot = red[0] + red[1] + red[2] + red[3];
        scale_inv[blockIdx.x] = 1.0f / sqrtf(tot);
    }
}

// ---------------------------------------------------------------------------
__global__ void k_deg(const int* __restrict__ A, int* __restrict__ cnt, int E) {
    int e = blockIdx.x * 256 + threadIdx.x;
    if (e >= E) return;
    atomicAdd(&cnt[A[E + e]], 1);
}

// scan phase 1: per-block sums (coalesced), plus dinv
__global__ __launch_bounds__(256) void k_scan_part(const int* __restrict__ cnt,
                                                   int* __restrict__ partial,
                                                   float* __restrict__ dinv, int n) {
    int idx = blockIdx.x * 256 + threadIdx.x;
    int v = (idx < n) ? cnt[idx] : 0;
    if (idx < n) dinv[idx] = rsqrtf((float)v + 1.0f);
    int s = v;
    #pragma unroll
    for (int off = 32; off >= 1; off >>= 1) s += __shfl_down(s, off);
    __shared__ int red[4];
    int lane = threadIdx.x & 63, wid = threadIdx.x >> 6;
    if (lane == 0) red[wid] = s;
    __syncthreads();
    if (threadIdx.x == 0) partial[blockIdx.x] = red[0] + red[1] + red[2] + red[3];
}

// scan phase 2: single small block scans the partials -> exclusive base per block
__global__ __launch_bounds__(256) void k_scan_mid(const int* __restrict__ partial,
                                                  int* __restrict__ base,
                                                  int* __restrict__ ptr, int nb, int n) {
    int tid = threadIdx.x;
    int v = (tid < nb) ? partial[tid] : 0;
    int lane = tid & 63, wid = tid >> 6;
    int sc = v;
    #pragma unroll
    for (int off = 1; off < 64; off <<= 1) {
        int t = __shfl_up(sc, off);
        if (lane >= off) sc += t;
    }
    __shared__ int wsum[4], wpre[4];
    if (lane == 63) wsum[wid] = sc;
    __syncthreads();
    if (tid == 0) {
        int acc = 0;
        #pragma unroll
        for (int w = 0; w < 4; ++w) { wpre[w] = acc; acc += wsum[w]; }
    }
    __syncthreads();
    int excl = wpre[wid] + sc - v;
    if (tid < nb) base[tid] = excl;
    if (tid == 255) ptr[n] = wpre[3] + sc;   // total edges
}

// scan phase 3: per-block exclusive scan + base -> ptr
__global__ __launch_bounds__(256) void k_scan_final(const int* __restrict__ cnt,
                                                    const int* __restrict__ base,
                                                    int* __restrict__ ptr, int n) {
    int idx = blockIdx.x * 256 + threadIdx.x;
    int v = (idx < n) ? cnt[idx] : 0;
    int tid = threadIdx.x, lane = tid & 63, wid = tid >> 6;
    int sc = v;
    #pragma unroll
    for (int off = 1; off < 64; off <<= 1) {
        int t = __shfl_up(sc, off);
        if (lane >= off) sc += t;
    }
    __shared__ int wsum[4], wpre[4];
    if (lane == 63) wsum[wid] = sc;
    __syncthreads();
    if (tid == 0) {
        int acc = 0;
        #pragma unroll
        for (int w = 0; w < 4; ++w) { wpre[w] = acc; acc += wsum[w]; }
    }
    __syncthreads();
    if (idx < n) ptr[idx] = base[blockIdx.x] + wpre[wid] + sc - v;
}

// fill CSR
__global__ void k_fill(const int* __restrict__ A, const int* __restrict__ ptr,
                       int* __restrict__ fill, const float* __restrict__ dinv,
                       int* __restrict__ csrc, float* __restrict__ cw, int E) {
    int e = blockIdx.x * 256 + threadIdx.x;
    if (e >= E) return;
    int s = A[e];
    int d = A[E + e];
    int pos = ptr[d] + atomicAdd(&fill[d], 1);
    csrc[pos] = s;
    cw[pos] = dinv[s];
}

// ---------------------------------------------------------------------------
// fp32 GEMM: out[n][o] = scale * sum_k X[n][k] * W[o][k]  (K=O=128)
// 128 nodes x 128 outs per 256-thread block; 8x8 per thread.
__global__ __launch_bounds__(256) void k_gemm128(const float* __restrict__ X,
                                                 const float* __restrict__ W,
                                                 const float* __restrict__ scale_ptr,
                                                 float* __restrict__ out, int N) {
    __shared__ float Xs[16][132];   // [k][node]
    __shared__ float Ws[16][128];   // [k][out]
    int tid = threadIdx.x;
    int n0 = blockIdx.x * 128;
    float scale = scale_ptr[0];
    int tx = tid & 15;   // outs tx*8 .. +7
    int ty = tid >> 4;   // nodes ty*8 .. +7
    float acc[8][8] = {};
    for (int k0 = 0; k0 < DIM; k0 += 16) {
        #pragma unroll
        for (int r = 0; r < 2; ++r) {   // X tile: 512 float4, coalesced
            int f = tid + 256 * r;
            int row = f >> 2, kq = f & 3;
            int gr = n0 + row;
            if (gr >= N) gr = N - 1;
            const float4 x4 = *reinterpret_cast<const float4*>(&X[(size_t)gr * DIM + k0 + kq * 4]);
            Xs[kq * 4 + 0][row] = x4.x;
            Xs[kq * 4 + 1][row] = x4.y;
            Xs[kq * 4 + 2][row] = x4.z;
            Xs[kq * 4 + 3][row] = x4.w;
        }
        #pragma unroll
        for (int r = 0; r < 2; ++r) {   // W tile
            int f = tid + 256 * r;
            int o = f >> 2, kq = f & 3;
            const float4 w4 = *reinterpret_cast<const float4*>(&W[(size_t)o * DIM + k0 + kq * 4]);
            Ws[kq * 4 + 0][o] = w4.x;
            Ws[kq * 4 + 1][o] = w4.y;
            Ws[kq * 4 + 2][o] = w4.z;
            Ws[kq * 4 + 3][o] = w4.w;
        }
        __syncthreads();
        #pragma unroll
        for (int k = 0; k < 16; ++k) {
            float4 wa = *reinterpret_cast<const float4*>(&Ws[k][tx * 8]);
            float4 wb = *reinterpret_cast<const float4*>(&Ws[k][tx * 8 + 4]);
            float4 xa = *reinterpret_cast<const float4*>(&Xs[k][ty * 8]);
            float4 xb = *reinterpret_cast<const float4*>(&Xs[k][ty * 8 + 4]);
            float xv[8] = {xa.x, xa.y, xa.z, xa.w, xb.x, xb.y, xb.z, xb.w};
            float wv[8] = {wa.x, wa.y, wa.z, wa.w, wb.x, wb.y, wb.z, wb.w};
            #pragma unroll
            for (int i = 0; i < 8; ++i)
                #pragma unroll
                for (int j = 0; j < 8; ++j)
                    acc[i][j] = fmaf(xv[i], wv[j], acc[i][j]);
        }
        __syncthreads();
    }
    #pragma unroll
    for (int i = 0; i < 8; ++i) {
        int row = n0 + ty * 8 + i;
        if (row < N) {
            float4 oa = make_float4(acc[i][0] * scale, acc[i][1] * scale,
                                    acc[i][2] * scale, acc[i][3] * scale);
            float4 ob = make_float4(acc[i][4] * scale, acc[i][5] * scale,
                                    acc[i][6] * scale, acc[i][7] * scale);
            *reinterpret_cast<float4*>(&out[(size_t)row * DIM + tx * 8]) = oa;
            *reinterpret_cast<float4*>(&out[(size_t)row * DIM + tx * 8 + 4]) = ob;
        }
    }
}

// ---------------------------------------------------------------------------
// aggregation + self-loop + bias (+ relu + residual)
__global__ __launch_bounds__(256) void k_agg(const float* __restrict__ G,
                                             const float* __restrict__ bias,
                                             const float* __restrict__ dinv,
                                             const int* __restrict__ ptr,
                                             const int* __restrict__ csrc,
                                             const float* __restrict__ cw,
                                             const float* __restrict__ skip,
                                             float* __restrict__ out,
                                             int relu_res, int N) {
    int n = blockIdx.x * 8 + (threadIdx.x >> 5);
    if (n >= N) return;
    int l = threadIdx.x & 31;
    const float4* __restrict__ Gv = reinterpret_cast<const float4*>(G);
    int beg = ptr[n], end = ptr[n + 1];
    float4 a0 = make_float4(0.f, 0.f, 0.f, 0.f), a1 = a0, a2 = a0, a3 = a0;
    int e = beg;
    for (; e + 4 <= end; e += 4) {
        int s0 = csrc[e + 0], s1 = csrc[e + 1], s2 = csrc[e + 2], s3 = csrc[e + 3];
        float w0 = cw[e + 0], w1 = cw[e + 1], w2 = cw[e + 2], w3 = cw[e + 3];
        float4 g0 = Gv[(size_t)s0 * 32 + l];
        float4 g1 = Gv[(size_t)s1 * 32 + l];
        float4 g2 = Gv[(size_t)s2 * 32 + l];
        float4 g3 = Gv[(size_t)s3 * 32 + l];
        fma4(a0, w0, g0);
        fma4(a1, w1, g1);
        fma4(a2, w2, g2);
        fma4(a3, w3, g3);
    }
    for (; e < end; ++e) {
        int s = csrc[e];
        float w = cw[e];
        float4 g = Gv[(size_t)s * 32 + l];
        fma4(a0, w, g);
    }
    float4 acc;
    acc.x = (a0.x + a1.x) + (a2.x + a3.x);
    acc.y = (a0.y + a1.y) + (a2.y + a3.y);
    acc.z = (a0.z + a1.z) + (a2.z + a3.z);
    acc.w = (a0.w + a1.w) + (a2.w + a3.w);

    float di = dinv[n];
    float d2 = di * di;
    float4 gs = Gv[(size_t)n * 32 + l];
    float4 b4 = reinterpret_cast<const float4*>(bias)[l];
    float4 v;
    v.x = fmaf(di, acc.x, fmaf(d2, gs.x, b4.x));
    v.y = fmaf(di, acc.y, fmaf(d2, gs.y, b4.y));
    v.z = fmaf(di, acc.z, fmaf(d2, gs.z, b4.z));
    v.w = fmaf(di, acc.w, fmaf(d2, gs.w, b4.w));
    if (relu_res) {
        float4 s4 = reinterpret_cast<const float4*>(skip)[(size_t)n * 32 + l];
        v.x = fmaxf(v.x, 0.f) + s4.x;
        v.y = fmaxf(v.y, 0.f) + s4.y;
        v.z = fmaxf(v.z, 0.f) + s4.z;
        v.w = fmaxf(v.w, 0.f) + s4.w;
    }
    reinterpret_cast<float4*>(out)[(size_t)n * 32 + l] = v;
}

// ---------------------------------------------------------------------------
// final classifier as LDS-tiled GEMM (outs padded 40->64)
__global__ __launch_bounds__(256) void k_final(const float* __restrict__ H,
                                               const float* __restrict__ Wf,
                                               const float* __restrict__ bf,
                                               float* __restrict__ out, int N) {
    __shared__ float Xs[16][68];
    __shared__ float Ws[16][64];
    int tid = threadIdx.x;
    int n0 = blockIdx.x * 64;
    int tx = tid & 15;
    int ty = tid >> 4;
    float acc[4][4] = {};
    for (int k0 = 0; k0 < DIM; k0 += 16) {
        {
            int j = tid >> 2, kq = tid & 3;
            int row = n0 + j;
            if (row >= N) row = N - 1;
            const float4 x4 = *reinterpret_cast<const float4*>(&H[(size_t)row * DIM + k0 + kq * 4]);
            Xs[kq * 4 + 0][j] = x4.x;
            Xs[kq * 4 + 1][j] = x4.y;
            Xs[kq * 4 + 2][j] = x4.z;
            Xs[kq * 4 + 3][j] = x4.w;
        }
        {
            int o = tid >> 2, kq = tid & 3;
            int om = o < NCLS ? o : o - NCLS;
            const float4 w4 = *reinterpret_cast<const float4*>(&Wf[(size_t)om * DIM + k0 + kq * 4]);
            Ws[kq * 4 + 0][o] = w4.x;
            Ws[kq * 4 + 1][o] = w4.y;
            Ws[kq * 4 + 2][o] = w4.z;
            Ws[kq * 4 + 3][o] = w4.w;
        }
        __syncthreads();
        #pragma unroll
        for (int k = 0; k < 16; ++k) {
            float4 w = *reinterpret_cast<const float4*>(&Ws[k][tx * 4]);
            float4 x = *reinterpret_cast<const float4*>(&Xs[k][ty * 4]);
            float xv[4] = {x.x, x.y, x.z, x.w};
            #pragma unroll
            for (int i = 0; i < 4; ++i) {
                acc[i][0] = fmaf(xv[i], w.x, acc[i][0]);
                acc[i][1] = fmaf(xv[i], w.y, acc[i][1]);
                acc[i][2] = fmaf(xv[i], w.z, acc[i][2]);
                acc[i][3] = fmaf(xv[i], w.w, acc[i][3]);
            }
        }
        __syncthreads();
    }
    if (tx >= 10) return;
    float4 b4 = make_float4(bf[tx * 4], bf[tx * 4 + 1], bf[tx * 4 + 2], bf[tx * 4 + 3]);
    #pragma unroll
    for (int i = 0; i < 4; ++i) {
        int row = n0 + ty * 4 + i;
        if (row < N) {
            float* op = &out[(size_t)row * NCLS + tx * 4];
            op[0] = acc[i][0] + b4.x;
            op[1] = acc[i][1] + b4.y;
            op[2] = acc[i][2] + b4.z;
            op[3] = acc[i][3] + b4.w;
        }
    }
}

// ---------------------------------------------------------------------------
extern "C" void kernel_launch(void* const* d_in, const int* in_sizes, int n_in,
                              void* d_out, int out_size, void* d_ws, size_t ws_size,
                              hipStream_t stream) {
    (void)in_sizes; (void)n_in; (void)out_size; (void)ws_size;
    const float* X  = (const float*)d_in[0];
    const int*   A  = (const int*)d_in[1];
    const float* W0 = (const float*)d_in[2];
    const float* b0 = (const float*)d_in[3];
    const float* W1 = (const float*)d_in[4];
    const float* b1 = (const float*)d_in[5];
    const float* W2 = (const float*)d_in[6];
    const float* b2 = (const float*)d_in[7];
    const float* W3 = (const float*)d_in[8];
    const float* b3 = (const float*)d_in[9];
    const float* Wf = (const float*)d_in[10];
    const float* bf = (const float*)d_in[11];
    float* out = (float*)d_out;

    char* base_ws = (char*)d_ws;
    size_t off = 0;
    auto alloc = [&](size_t bytes) -> char* {
        char* p = base_ws + off;
        off = (off + bytes + 255) & ~(size_t)255;
        return p;
    };
    float* scale_inv = (float*)alloc(4 * sizeof(float));
    int*   deg   = (int*)alloc(N_NODES_C * sizeof(int));
    int*   fill  = (int*)alloc(N_NODES_C * sizeof(int));
    int*   ptr   = (int*)alloc((N_NODES_C + 1) * sizeof(int));
    float* dinv  = (float*)alloc(N_NODES_C * sizeof(float));
    int*   part  = (int*)alloc(SCAN_NB * sizeof(int));
    int*   bbase = (int*)alloc(SCAN_NB * sizeof(int));
    int*   csrc  = (int*)alloc(N_EDGES_C * sizeof(int));
    float* cw    = (float*)alloc(N_EDGES_C * sizeof(float));
    float* G     = (float*)alloc((size_t)N_NODES_C * DIM * sizeof(float));
    float* H1    = (float*)alloc((size_t)N_NODES_C * DIM * sizeof(float));
    float* H2    = (float*)alloc((size_t)N_NODES_C * DIM * sizeof(float));

    hipMemsetAsync(deg, 0, N_NODES_C * sizeof(int), stream);
    hipMemsetAsync(fill, 0, N_NODES_C * sizeof(int), stream);

    k_scales<<<4, 256, 0, stream>>>(W0, W1, W2, W3, scale_inv);
    k_deg<<<(N_EDGES_C + 255) / 256, 256, 0, stream>>>(A, deg, N_EDGES_C);
    k_scan_part<<<SCAN_NB, 256, 0, stream>>>(deg, part, dinv, N_NODES_C);
    k_scan_mid<<<1, 256, 0, stream>>>(part, bbase, ptr, SCAN_NB, N_NODES_C);
    k_scan_final<<<SCAN_NB, 256, 0, stream>>>(deg, bbase, ptr, N_NODES_C);
    k_fill<<<(N_EDGES_C + 255) / 256, 256, 0, stream>>>(A, ptr, fill, dinv, csrc, cw, N_EDGES_C);

    const int gemm_grid = (N_NODES_C + 127) / 128;
    const int agg_grid  = (N_NODES_C + 7) / 8;

    // layer 0
    k_gemm128<<<gemm_grid, 256, 0, stream>>>(X, W0, scale_inv + 0, G, N_NODES_C);
    k_agg<<<agg_grid, 256, 0, stream>>>(G, b0, dinv, ptr, csrc, cw, nullptr, H1, 0, N_NODES_C);
    // layer 1
    k_gemm128<<<gemm_grid, 256, 0, stream>>>(H1, W1, scale_inv + 1, G, N_NODES_C);
    k_agg<<<agg_grid, 256, 0, stream>>>(G, b1, dinv, ptr, csrc, cw, H1, H2, 1, N_NODES_C);
    // layer 2
    k_gemm128<<<gemm_grid, 256, 0, stream>>>(H2, W2, scale_inv + 2, G, N_NODES_C);
    k_agg<<<agg_grid, 256, 0, stream>>>(G, b2, dinv, ptr, csrc, cw, H2, H1, 1, N_NODES_C);
    // layer 3
    k_gemm128<<<gemm_grid, 256, 0, stream>>>(H1, W3, scale_inv + 3, G, N_NODES_C);
    k_agg<<<agg_grid, 256, 0, stream>>>(G, b3, dinv, ptr, csrc, cw, H1, H2, 1, N_NODES_C);
    // final classifier
    k_final<<<(N_NODES_C + 63) / 64, 256, 0, stream>>>(H2, Wf, bf, out, N_NODES_C);
}

// Round 5
// 409.416 us; speedup vs baseline: 2.4658x; 1.2655x over previous
//
#include <hip/hip_runtime.h>

#define N_NODES_C 50000
#define N_EDGES_C 800000
#define DIM 128
#define NCLS 40
#define SCAN_NB ((N_NODES_C + 255) / 256)

__device__ inline float bf2f(unsigned short u) {
    union { unsigned int i; float f; } c;
    c.i = ((unsigned int)u) << 16;
    return c.f;
}
__device__ inline unsigned short f2bf(float f) {
    union { float f; unsigned int i; } c;
    c.f = f;
    unsigned int x = c.i;
    x += 0x7fffu + ((x >> 16) & 1u);   // RNE
    return (unsigned short)(x >> 16);
}
__device__ inline void fma4b(float4& a, float w, const ushort4& u) {
    a.x = fmaf(w, bf2f(u.x), a.x);
    a.y = fmaf(w, bf2f(u.y), a.y);
    a.z = fmaf(w, bf2f(u.z), a.z);
    a.w = fmaf(w, bf2f(u.w), a.w);
}

// ---------------------------------------------------------------------------
// Frobenius-norm scales
__global__ __launch_bounds__(256) void k_scales(const float* __restrict__ W0,
                                                const float* __restrict__ W1,
                                                const float* __restrict__ W2,
                                                const float* __restrict__ W3,
                                                float* __restrict__ scale_inv) {
    const float* W = blockIdx.x == 0 ? W0 : blockIdx.x == 1 ? W1 : blockIdx.x == 2 ? W2 : W3;
    float s = 0.f;
    for (int i = threadIdx.x; i < DIM * DIM; i += 256) {
        float v = W[i];
        s += v * v;
    }
    #pragma unroll
    for (int off = 32; off >= 1; off >>= 1) s += __shfl_down(s, off);
    __shared__ float red[4];
    int lane = threadIdx.x & 63, wid = threadIdx.x >> 6;
    if (lane == 0) red[wid] = s;
    __syncthreads();
    if (threadIdx.x == 0) {
        float tot = red[0] + red[1] + red[2] + red[3];
        scale_inv[blockIdx.x] = 1.0f / sqrtf(tot);
    }
}

// ---------------------------------------------------------------------------
__global__ void k_deg(const int* __restrict__ A, int* __restrict__ cnt, int E) {
    int e = blockIdx.x * 256 + threadIdx.x;
    if (e >= E) return;
    atomicAdd(&cnt[A[E + e]], 1);
}

// scan phase 1: per-block sums (coalesced), plus dinv
__global__ __launch_bounds__(256) void k_scan_part(const int* __restrict__ cnt,
                                                   int* __restrict__ partial,
                                                   float* __restrict__ dinv, int n) {
    int idx = blockIdx.x * 256 + threadIdx.x;
    int v = (idx < n) ? cnt[idx] : 0;
    if (idx < n) dinv[idx] = rsqrtf((float)v + 1.0f);
    int s = v;
    #pragma unroll
    for (int off = 32; off >= 1; off >>= 1) s += __shfl_down(s, off);
    __shared__ int red[4];
    int lane = threadIdx.x & 63, wid = threadIdx.x >> 6;
    if (lane == 0) red[wid] = s;
    __syncthreads();
    if (threadIdx.x == 0) partial[blockIdx.x] = red[0] + red[1] + red[2] + red[3];
}

// scan phase 2: single block scans the partials -> exclusive base per block
__global__ __launch_bounds__(256) void k_scan_mid(const int* __restrict__ partial,
                                                  int* __restrict__ base,
                                                  int* __restrict__ ptr, int nb, int n) {
    int tid = threadIdx.x;
    int v = (tid < nb) ? partial[tid] : 0;
    int lane = tid & 63, wid = tid >> 6;
    int sc = v;
    #pragma unroll
    for (int off = 1; off < 64; off <<= 1) {
        int t = __shfl_up(sc, off);
        if (lane >= off) sc += t;
    }
    __shared__ int wsum[4], wpre[4];
    if (lane == 63) wsum[wid] = sc;
    __syncthreads();
    if (tid == 0) {
        int acc = 0;
        #pragma unroll
        for (int w = 0; w < 4; ++w) { wpre[w] = acc; acc += wsum[w]; }
    }
    __syncthreads();
    int excl = wpre[wid] + sc - v;
    if (tid < nb) base[tid] = excl;
    if (tid == 255) ptr[n] = wpre[3] + sc;
}

// scan phase 3: per-block exclusive scan + base -> ptr
__global__ __launch_bounds__(256) void k_scan_final(const int* __restrict__ cnt,
                                                    const int* __restrict__ base,
                                                    int* __restrict__ ptr, int n) {
    int idx = blockIdx.x * 256 + threadIdx.x;
    int v = (idx < n) ? cnt[idx] : 0;
    int tid = threadIdx.x, lane = tid & 63, wid = tid >> 6;
    int sc = v;
    #pragma unroll
    for (int off = 1; off < 64; off <<= 1) {
        int t = __shfl_up(sc, off);
        if (lane >= off) sc += t;
    }
    __shared__ int wsum[4], wpre[4];
    if (lane == 63) wsum[wid] = sc;
    __syncthreads();
    if (tid == 0) {
        int acc = 0;
        #pragma unroll
        for (int w = 0; w < 4; ++w) { wpre[w] = acc; acc += wsum[w]; }
    }
    __syncthreads();
    if (idx < n) ptr[idx] = base[blockIdx.x] + wpre[wid] + sc - v;
}

// fill CSR
__global__ void k_fill(const int* __restrict__ A, const int* __restrict__ ptr,
                       int* __restrict__ fill, const float* __restrict__ dinv,
                       int* __restrict__ csrc, float* __restrict__ cw, int E) {
    int e = blockIdx.x * 256 + threadIdx.x;
    if (e >= E) return;
    int s = A[e];
    int d = A[E + e];
    int pos = ptr[d] + atomicAdd(&fill[d], 1);
    csrc[pos] = s;
    cw[pos] = dinv[s];
}

// ---------------------------------------------------------------------------
// fp32 GEMM -> bf16 output: Gb[n][o] = bf16(scale * sum_k X[n][k] * W[o][k])
// 128 nodes x 128 outs per 256-thread block; 8x8 per thread.
__global__ __launch_bounds__(256) void k_gemm128(const float* __restrict__ X,
                                                 const float* __restrict__ W,
                                                 const float* __restrict__ scale_ptr,
                                                 unsigned short* __restrict__ Gb, int N) {
    __shared__ float Xs[16][132];
    __shared__ float Ws[16][128];
    int tid = threadIdx.x;
    int n0 = blockIdx.x * 128;
    float scale = scale_ptr[0];
    int tx = tid & 15;
    int ty = tid >> 4;
    float acc[8][8] = {};
    for (int k0 = 0; k0 < DIM; k0 += 16) {
        #pragma unroll
        for (int r = 0; r < 2; ++r) {
            int f = tid + 256 * r;
            int row = f >> 2, kq = f & 3;
            int gr = n0 + row;
            if (gr >= N) gr = N - 1;
            const float4 x4 = *reinterpret_cast<const float4*>(&X[(size_t)gr * DIM + k0 + kq * 4]);
            Xs[kq * 4 + 0][row] = x4.x;
            Xs[kq * 4 + 1][row] = x4.y;
            Xs[kq * 4 + 2][row] = x4.z;
            Xs[kq * 4 + 3][row] = x4.w;
        }
        #pragma unroll
        for (int r = 0; r < 2; ++r) {
            int f = tid + 256 * r;
            int o = f >> 2, kq = f & 3;
            const float4 w4 = *reinterpret_cast<const float4*>(&W[(size_t)o * DIM + k0 + kq * 4]);
            Ws[kq * 4 + 0][o] = w4.x;
            Ws[kq * 4 + 1][o] = w4.y;
            Ws[kq * 4 + 2][o] = w4.z;
            Ws[kq * 4 + 3][o] = w4.w;
        }
        __syncthreads();
        #pragma unroll
        for (int k = 0; k < 16; ++k) {
            float4 wa = *reinterpret_cast<const float4*>(&Ws[k][tx * 8]);
            float4 wb = *reinterpret_cast<const float4*>(&Ws[k][tx * 8 + 4]);
            float4 xa = *reinterpret_cast<const float4*>(&Xs[k][ty * 8]);
            float4 xb = *reinterpret_cast<const float4*>(&Xs[k][ty * 8 + 4]);
            float xv[8] = {xa.x, xa.y, xa.z, xa.w, xb.x, xb.y, xb.z, xb.w};
            float wv[8] = {wa.x, wa.y, wa.z, wa.w, wb.x, wb.y, wb.z, wb.w};
            #pragma unroll
            for (int i = 0; i < 8; ++i)
                #pragma unroll
                for (int j = 0; j < 8; ++j)
                    acc[i][j] = fmaf(xv[i], wv[j], acc[i][j]);
        }
        __syncthreads();
    }
    #pragma unroll
    for (int i = 0; i < 8; ++i) {
        int row = n0 + ty * 8 + i;
        if (row < N) {
            unsigned int w[4];
            #pragma unroll
            for (int j = 0; j < 4; ++j) {
                unsigned int lo = f2bf(acc[i][2 * j] * scale);
                unsigned int hi = f2bf(acc[i][2 * j + 1] * scale);
                w[j] = lo | (hi << 16);
            }
            *reinterpret_cast<uint4*>(&Gb[(size_t)row * DIM + tx * 8]) =
                make_uint4(w[0], w[1], w[2], w[3]);
        }
    }
}

// ---------------------------------------------------------------------------
// aggregation over bf16 G + self-loop + bias (+ relu + residual), fp32 accum.
// 8 nodes per 256-block; 32 lanes per node; ushort4 (8B) per lane; 8-deep unroll.
__global__ __launch_bounds__(256) void k_agg(const unsigned short* __restrict__ Gb,
                                             const float* __restrict__ bias,
                                             const float* __restrict__ dinv,
                                             const int* __restrict__ ptr,
                                             const int* __restrict__ csrc,
                                             const float* __restrict__ cw,
                                             const float* __restrict__ skip,
                                             float* __restrict__ out,
                                             int relu_res, int N) {
    int n = blockIdx.x * 8 + (threadIdx.x >> 5);
    if (n >= N) return;
    int l = threadIdx.x & 31;
    const ushort4* __restrict__ Gv = reinterpret_cast<const ushort4*>(Gb);
    int beg = ptr[n], end = ptr[n + 1];
    float4 a0 = make_float4(0.f, 0.f, 0.f, 0.f), a1 = a0, a2 = a0, a3 = a0;
    int e = beg;
    for (; e + 8 <= end; e += 8) {
        int s0 = csrc[e + 0], s1 = csrc[e + 1], s2 = csrc[e + 2], s3 = csrc[e + 3];
        int s4 = csrc[e + 4], s5 = csrc[e + 5], s6 = csrc[e + 6], s7 = csrc[e + 7];
        float w0 = cw[e + 0], w1 = cw[e + 1], w2 = cw[e + 2], w3 = cw[e + 3];
        float w4 = cw[e + 4], w5 = cw[e + 5], w6 = cw[e + 6], w7 = cw[e + 7];
        ushort4 g0 = Gv[(size_t)s0 * 32 + l];
        ushort4 g1 = Gv[(size_t)s1 * 32 + l];
        ushort4 g2 = Gv[(size_t)s2 * 32 + l];
        ushort4 g3 = Gv[(size_t)s3 * 32 + l];
        ushort4 g4 = Gv[(size_t)s4 * 32 + l];
        ushort4 g5 = Gv[(size_t)s5 * 32 + l];
        ushort4 g6 = Gv[(size_t)s6 * 32 + l];
        ushort4 g7 = Gv[(size_t)s7 * 32 + l];
        fma4b(a0, w0, g0);
        fma4b(a1, w1, g1);
        fma4b(a2, w2, g2);
        fma4b(a3, w3, g3);
        fma4b(a0, w4, g4);
        fma4b(a1, w5, g5);
        fma4b(a2, w6, g6);
        fma4b(a3, w7, g7);
    }
    for (; e + 4 <= end; e += 4) {
        int s0 = csrc[e + 0], s1 = csrc[e + 1], s2 = csrc[e + 2], s3 = csrc[e + 3];
        float w0 = cw[e + 0], w1 = cw[e + 1], w2 = cw[e + 2], w3 = cw[e + 3];
        ushort4 g0 = Gv[(size_t)s0 * 32 + l];
        ushort4 g1 = Gv[(size_t)s1 * 32 + l];
        ushort4 g2 = Gv[(size_t)s2 * 32 + l];
        ushort4 g3 = Gv[(size_t)s3 * 32 + l];
        fma4b(a0, w0, g0);
        fma4b(a1, w1, g1);
        fma4b(a2, w2, g2);
        fma4b(a3, w3, g3);
    }
    for (; e < end; ++e) {
        int s = csrc[e];
        float w = cw[e];
        ushort4 g = Gv[(size_t)s * 32 + l];
        fma4b(a0, w, g);
    }
    float4 acc;
    acc.x = (a0.x + a1.x) + (a2.x + a3.x);
    acc.y = (a0.y + a1.y) + (a2.y + a3.y);
    acc.z = (a0.z + a1.z) + (a2.z + a3.z);
    acc.w = (a0.w + a1.w) + (a2.w + a3.w);

    float di = dinv[n];
    float d2 = di * di;
    ushort4 gu = Gv[(size_t)n * 32 + l];
    float4 gs = make_float4(bf2f(gu.x), bf2f(gu.y), bf2f(gu.z), bf2f(gu.w));
    float4 b4 = reinterpret_cast<const float4*>(bias)[l];
    float4 v;
    v.x = fmaf(di, acc.x, fmaf(d2, gs.x, b4.x));
    v.y = fmaf(di, acc.y, fmaf(d2, gs.y, b4.y));
    v.z = fmaf(di, acc.z, fmaf(d2, gs.z, b4.z));
    v.w = fmaf(di, acc.w, fmaf(d2, gs.w, b4.w));
    if (relu_res) {
        float4 s4 = reinterpret_cast<const float4*>(skip)[(size_t)n * 32 + l];
        v.x = fmaxf(v.x, 0.f) + s4.x;
        v.y = fmaxf(v.y, 0.f) + s4.y;
        v.z = fmaxf(v.z, 0.f) + s4.z;
        v.w = fmaxf(v.w, 0.f) + s4.w;
    }
    reinterpret_cast<float4*>(out)[(size_t)n * 32 + l] = v;
}

// ---------------------------------------------------------------------------
// final classifier as LDS-tiled GEMM (outs padded 40->64), fp32 in/out
__global__ __launch_bounds__(256) void k_final(const float* __restrict__ H,
                                               const float* __restrict__ Wf,
                                               const float* __restrict__ bf,
                                               float* __restrict__ out, int N) {
    __shared__ float Xs[16][68];
    __shared__ float Ws[16][64];
    int tid = threadIdx.x;
    int n0 = blockIdx.x * 64;
    int tx = tid & 15;
    int ty = tid >> 4;
    float acc[4][4] = {};
    for (int k0 = 0; k0 < DIM; k0 += 16) {
        {
            int j = tid >> 2, kq = tid & 3;
            int row = n0 + j;
            if (row >= N) row = N - 1;
            const float4 x4 = *reinterpret_cast<const float4*>(&H[(size_t)row * DIM + k0 + kq * 4]);
            Xs[kq * 4 + 0][j] = x4.x;
            Xs[kq * 4 + 1][j] = x4.y;
            Xs[kq * 4 + 2][j] = x4.z;
            Xs[kq * 4 + 3][j] = x4.w;
        }
        {
            int o = tid >> 2, kq = tid & 3;
            int om = o < NCLS ? o : o - NCLS;
            const float4 w4 = *reinterpret_cast<const float4*>(&Wf[(size_t)om * DIM + k0 + kq * 4]);
            Ws[kq * 4 + 0][o] = w4.x;
            Ws[kq * 4 + 1][o] = w4.y;
            Ws[kq * 4 + 2][o] = w4.z;
            Ws[kq * 4 + 3][o] = w4.w;
        }
        __syncthreads();
        #pragma unroll
        for (int k = 0; k < 16; ++k) {
            float4 w = *reinterpret_cast<const float4*>(&Ws[k][tx * 4]);
            float4 x = *reinterpret_cast<const float4*>(&Xs[k][ty * 4]);
            float xv[4] = {x.x, x.y, x.z, x.w};
            #pragma unroll
            for (int i = 0; i < 4; ++i) {
                acc[i][0] = fmaf(xv[i], w.x, acc[i][0]);
                acc[i][1] = fmaf(xv[i], w.y, acc[i][1]);
                acc[i][2] = fmaf(xv[i], w.z, acc[i][2]);
                acc[i][3] = fmaf(xv[i], w.w, acc[i][3]);
            }
        }
        __syncthreads();
    }
    if (tx >= 10) return;
    float4 b4 = make_float4(bf[tx * 4], bf[tx * 4 + 1], bf[tx * 4 + 2], bf[tx * 4 + 3]);
    #pragma unroll
    for (int i = 0; i < 4; ++i) {
        int row = n0 + ty * 4 + i;
        if (row < N) {
            float* op = &out[(size_t)row * NCLS + tx * 4];
            op[0] = acc[i][0] + b4.x;
            op[1] = acc[i][1] + b4.y;
            op[2] = acc[i][2] + b4.z;
            op[3] = acc[i][3] + b4.w;
        }
    }
}

// ---------------------------------------------------------------------------
extern "C" void kernel_launch(void* const* d_in, const int* in_sizes, int n_in,
                              void* d_out, int out_size, void* d_ws, size_t ws_size,
                              hipStream_t stream) {
    (void)in_sizes; (void)n_in; (void)out_size; (void)ws_size;
    const float* X  = (const float*)d_in[0];
    const int*   A  = (const int*)d_in[1];
    const float* W0 = (const float*)d_in[2];
    const float* b0 = (const float*)d_in[3];
    const float* W1 = (const float*)d_in[4];
    const float* b1 = (const float*)d_in[5];
    const float* W2 = (const float*)d_in[6];
    const float* b2 = (const float*)d_in[7];
    const float* W3 = (const float*)d_in[8];
    const float* b3 = (const float*)d_in[9];
    const float* Wf = (const float*)d_in[10];
    const float* bf = (const float*)d_in[11];
    float* out = (float*)d_out;

    char* base_ws = (char*)d_ws;
    size_t off = 0;
    auto alloc = [&](size_t bytes) -> char* {
        char* p = base_ws + off;
        off = (off + bytes + 255) & ~(size_t)255;
        return p;
    };
    float* scale_inv = (float*)alloc(4 * sizeof(float));
    int*   deg   = (int*)alloc(N_NODES_C * sizeof(int));
    int*   fill  = (int*)alloc(N_NODES_C * sizeof(int));
    int*   ptr   = (int*)alloc((N_NODES_C + 1) * sizeof(int));
    float* dinv  = (float*)alloc(N_NODES_C * sizeof(float));
    int*   part  = (int*)alloc(SCAN_NB * sizeof(int));
    int*   bbase = (int*)alloc(SCAN_NB * sizeof(int));
    int*   csrc  = (int*)alloc(N_EDGES_C * sizeof(int));
    float* cw    = (float*)alloc(N_EDGES_C * sizeof(float));
    unsigned short* Gb = (unsigned short*)alloc((size_t)N_NODES_C * DIM * sizeof(unsigned short));
    float* H1    = (float*)alloc((size_t)N_NODES_C * DIM * sizeof(float));
    float* H2    = (float*)alloc((size_t)N_NODES_C * DIM * sizeof(float));

    hipMemsetAsync(deg, 0, N_NODES_C * sizeof(int), stream);
    hipMemsetAsync(fill, 0, N_NODES_C * sizeof(int), stream);

    k_scales<<<4, 256, 0, stream>>>(W0, W1, W2, W3, scale_inv);
    k_deg<<<(N_EDGES_C + 255) / 256, 256, 0, stream>>>(A, deg, N_EDGES_C);
    k_scan_part<<<SCAN_NB, 256, 0, stream>>>(deg, part, dinv, N_NODES_C);
    k_scan_mid<<<1, 256, 0, stream>>>(part, bbase, ptr, SCAN_NB, N_NODES_C);
    k_scan_final<<<SCAN_NB, 256, 0, stream>>>(deg, bbase, ptr, N_NODES_C);
    k_fill<<<(N_EDGES_C + 255) / 256, 256, 0, stream>>>(A, ptr, fill, dinv, csrc, cw, N_EDGES_C);

    const int gemm_grid = (N_NODES_C + 127) / 128;
    const int agg_grid  = (N_NODES_C + 7) / 8;

    // layer 0
    k_gemm128<<<gemm_grid, 256, 0, stream>>>(X, W0, scale_inv + 0, Gb, N_NODES_C);
    k_agg<<<agg_grid, 256, 0, stream>>>(Gb, b0, dinv, ptr, csrc, cw, nullptr, H1, 0, N_NODES_C);
    // layer 1
    k_gemm128<<<gemm_grid, 256, 0, stream>>>(H1, W1, scale_inv + 1, Gb, N_NODES_C);
    k_agg<<<agg_grid, 256, 0, stream>>>(Gb, b1, dinv, ptr, csrc, cw, H1, H2, 1, N_NODES_C);
    // layer 2
    k_gemm128<<<gemm_grid, 256, 0, stream>>>(H2, W2, scale_inv + 2, Gb, N_NODES_C);
    k_agg<<<agg_grid, 256, 0, stream>>>(Gb, b2, dinv, ptr, csrc, cw, H2, H1, 1, N_NODES_C);
    // layer 3
    k_gemm128<<<gemm_grid, 256, 0, stream>>>(H1, W3, scale_inv + 3, Gb, N_NODES_C);
    k_agg<<<agg_grid, 256, 0, stream>>>(Gb, b3, dinv, ptr, csrc, cw, H1, H2, 1, N_NODES_C);
    // final classifier
    k_final<<<(N_NODES_C + 63) / 64, 256, 0, stream>>>(H2, Wf, bf, out, N_NODES_C);
}

// Round 6
// 374.101 us; speedup vs baseline: 2.6986x; 1.0944x over previous
//
#include <hip/hip_runtime.h>

#define N_NODES_C 50000
#define N_EDGES_C 800000
#define DIM 128
#define NCLS 40
#define SCAN_NB ((N_NODES_C + 255) / 256)

typedef __attribute__((ext_vector_type(8))) short bf16x8;
typedef __attribute__((ext_vector_type(4))) float f32x4;

__device__ inline float bf2f(unsigned short u) {
    union { unsigned int i; float f; } c;
    c.i = ((unsigned int)u) << 16;
    return c.f;
}
__device__ inline unsigned short f2bf(float f) {
    union { float f; unsigned int i; } c;
    c.f = f;
    unsigned int x = c.i;
    x += 0x7fffu + ((x >> 16) & 1u);   // RNE
    return (unsigned short)(x >> 16);
}
__device__ inline void fma4b(float4& a, float w, const ushort4& u) {
    a.x = fmaf(w, bf2f(u.x), a.x);
    a.y = fmaf(w, bf2f(u.y), a.y);
    a.z = fmaf(w, bf2f(u.z), a.z);
    a.w = fmaf(w, bf2f(u.w), a.w);
}

// ---------------------------------------------------------------------------
// Frobenius-norm scales (on fp32 W, matches reference)
__global__ __launch_bounds__(256) void k_scales(const float* __restrict__ W0,
                                                const float* __restrict__ W1,
                                                const float* __restrict__ W2,
                                                const float* __restrict__ W3,
                                                float* __restrict__ scale_inv) {
    const float* W = blockIdx.x == 0 ? W0 : blockIdx.x == 1 ? W1 : blockIdx.x == 2 ? W2 : W3;
    float s = 0.f;
    for (int i = threadIdx.x; i < DIM * DIM; i += 256) {
        float v = W[i];
        s += v * v;
    }
    #pragma unroll
    for (int off = 32; off >= 1; off >>= 1) s += __shfl_down(s, off);
    __shared__ float red[4];
    int lane = threadIdx.x & 63, wid = threadIdx.x >> 6;
    if (lane == 0) red[wid] = s;
    __syncthreads();
    if (threadIdx.x == 0) {
        float tot = red[0] + red[1] + red[2] + red[3];
        scale_inv[blockIdx.x] = 1.0f / sqrtf(tot);
    }
}

// fp32 -> bf16 bulk convert (4 elems/thread)
__global__ __launch_bounds__(256) void k_f2b(const float* __restrict__ in,
                                             unsigned short* __restrict__ outb, int n4) {
    int i = blockIdx.x * 256 + threadIdx.x;
    if (i >= n4) return;
    float4 v = reinterpret_cast<const float4*>(in)[i];
    reinterpret_cast<ushort4*>(outb)[i] =
        make_ushort4(f2bf(v.x), f2bf(v.y), f2bf(v.z), f2bf(v.w));
}

// weights fp32 -> bf16 (4 matrices into one buffer)
__global__ __launch_bounds__(256) void k_w2b(const float* __restrict__ W0,
                                             const float* __restrict__ W1,
                                             const float* __restrict__ W2,
                                             const float* __restrict__ W3,
                                             unsigned short* __restrict__ Wb) {
    int m = blockIdx.x >> 4;
    int idx = (blockIdx.x & 15) * 256 + threadIdx.x;   // 0..4095 float4s
    const float* W = m == 0 ? W0 : m == 1 ? W1 : m == 2 ? W2 : W3;
    float4 v = reinterpret_cast<const float4*>(W)[idx];
    reinterpret_cast<ushort4*>(Wb + (size_t)m * DIM * DIM)[idx] =
        make_ushort4(f2bf(v.x), f2bf(v.y), f2bf(v.z), f2bf(v.w));
}

// ---------------------------------------------------------------------------
__global__ void k_deg(const int* __restrict__ A, int* __restrict__ cnt, int E) {
    int e = blockIdx.x * 256 + threadIdx.x;
    if (e >= E) return;
    atomicAdd(&cnt[A[E + e]], 1);
}

__global__ __launch_bounds__(256) void k_scan_part(const int* __restrict__ cnt,
                                                   int* __restrict__ partial,
                                                   float* __restrict__ dinv, int n) {
    int idx = blockIdx.x * 256 + threadIdx.x;
    int v = (idx < n) ? cnt[idx] : 0;
    if (idx < n) dinv[idx] = rsqrtf((float)v + 1.0f);
    int s = v;
    #pragma unroll
    for (int off = 32; off >= 1; off >>= 1) s += __shfl_down(s, off);
    __shared__ int red[4];
    int lane = threadIdx.x & 63, wid = threadIdx.x >> 6;
    if (lane == 0) red[wid] = s;
    __syncthreads();
    if (threadIdx.x == 0) partial[blockIdx.x] = red[0] + red[1] + red[2] + red[3];
}

__global__ __launch_bounds__(256) void k_scan_mid(const int* __restrict__ partial,
                                                  int* __restrict__ base,
                                                  int* __restrict__ ptr, int nb, int n) {
    int tid = threadIdx.x;
    int v = (tid < nb) ? partial[tid] : 0;
    int lane = tid & 63, wid = tid >> 6;
    int sc = v;
    #pragma unroll
    for (int off = 1; off < 64; off <<= 1) {
        int t = __shfl_up(sc, off);
        if (lane >= off) sc += t;
    }
    __shared__ int wsum[4], wpre[4];
    if (lane == 63) wsum[wid] = sc;
    __syncthreads();
    if (tid == 0) {
        int acc = 0;
        #pragma unroll
        for (int w = 0; w < 4; ++w) { wpre[w] = acc; acc += wsum[w]; }
    }
    __syncthreads();
    int excl = wpre[wid] + sc - v;
    if (tid < nb) base[tid] = excl;
    if (tid == 255) ptr[n] = wpre[3] + sc;
}

__global__ __launch_bounds__(256) void k_scan_final(const int* __restrict__ cnt,
                                                    const int* __restrict__ base,
                                                    int* __restrict__ ptr, int n) {
    int idx = blockIdx.x * 256 + threadIdx.x;
    int v = (idx < n) ? cnt[idx] : 0;
    int tid = threadIdx.x, lane = tid & 63, wid = tid >> 6;
    int sc = v;
    #pragma unroll
    for (int off = 1; off < 64; off <<= 1) {
        int t = __shfl_up(sc, off);
        if (lane >= off) sc += t;
    }
    __shared__ int wsum[4], wpre[4];
    if (lane == 63) wsum[wid] = sc;
    __syncthreads();
    if (tid == 0) {
        int acc = 0;
        #pragma unroll
        for (int w = 0; w < 4; ++w) { wpre[w] = acc; acc += wsum[w]; }
    }
    __syncthreads();
    if (idx < n) ptr[idx] = base[blockIdx.x] + wpre[wid] + sc - v;
}

// fill CSR: one packed 8B write per edge {src, dinv[src]}
__global__ void k_fill(const int* __restrict__ A, const int* __restrict__ ptr,
                       int* __restrict__ fill, const float* __restrict__ dinv,
                       uint2* __restrict__ eidx, int E) {
    int e = blockIdx.x * 256 + threadIdx.x;
    if (e >= E) return;
    int s = A[e];
    int d = A[E + e];
    int pos = ptr[d] + atomicAdd(&fill[d], 1);
    eidx[pos] = make_uint2((unsigned)s, __float_as_uint(dinv[s]));
}

// ---------------------------------------------------------------------------
// bf16 MFMA GEMM: Gb[n][o] = bf16(scale * sum_k Xb[n][k] * Wb[o][k])
// block = 256 thr (4 waves); wave w: rows n0+w*16..+15, all 128 cols.
// A frag: lane l holds Xb[row=l&15][kc*32+(l>>4)*8 ..+7]  (16B contiguous)
// B frag: lane l holds Wb[col=ct*16+(l&15)][same k range]  (16B contiguous)
// D: col = lane&15, row = (lane>>4)*4 + reg   [m89-verified]
__global__ __launch_bounds__(256) void k_gemm_mfma(const unsigned short* __restrict__ Xb,
                                                   const unsigned short* __restrict__ Wb,
                                                   const float* __restrict__ scale_ptr,
                                                   unsigned short* __restrict__ Gb, int N) {
    int tid = threadIdx.x;
    int w = tid >> 6;
    int l = tid & 63;
    int l15 = l & 15;
    int lg = l >> 4;
    int arow = blockIdx.x * 64 + w * 16 + l15;
    if (arow >= N) arow = N - 1;
    float scale = scale_ptr[0];

    f32x4 acc[8];
    #pragma unroll
    for (int ct = 0; ct < 8; ++ct) acc[ct] = f32x4{0.f, 0.f, 0.f, 0.f};

    #pragma unroll
    for (int kc = 0; kc < 4; ++kc) {
        int ko = kc * 32 + lg * 8;
        bf16x8 a = *reinterpret_cast<const bf16x8*>(&Xb[(size_t)arow * DIM + ko]);
        #pragma unroll
        for (int ct = 0; ct < 8; ++ct) {
            bf16x8 b = *reinterpret_cast<const bf16x8*>(&Wb[(size_t)(ct * 16 + l15) * DIM + ko]);
            acc[ct] = __builtin_amdgcn_mfma_f32_16x16x32_bf16(a, b, acc[ct], 0, 0, 0);
        }
    }
    int outrow0 = blockIdx.x * 64 + w * 16 + lg * 4;
    #pragma unroll
    for (int r = 0; r < 4; ++r) {
        int row = outrow0 + r;
        if (row < N) {
            #pragma unroll
            for (int ct = 0; ct < 8; ++ct)
                Gb[(size_t)row * DIM + ct * 16 + l15] = f2bf(acc[ct][r] * scale);
        }
    }
}

// ---------------------------------------------------------------------------
// aggregation over bf16 G + self-loop + bias (+ relu + residual), fp32 accum.
// writes fp32 H (skip/classifier path) AND bf16 Hb (next GEMM input).
__global__ __launch_bounds__(256) void k_agg(const unsigned short* __restrict__ Gb,
                                             const float* __restrict__ bias,
                                             const float* __restrict__ dinv,
                                             const int* __restrict__ ptr,
                                             const uint2* __restrict__ eidx,
                                             const float* __restrict__ skip,
                                             float* __restrict__ out,
                                             unsigned short* __restrict__ outb,
                                             int relu_res, int N) {
    int n = blockIdx.x * 8 + (threadIdx.x >> 5);
    if (n >= N) return;
    int l = threadIdx.x & 31;
    const ushort4* __restrict__ Gv = reinterpret_cast<const ushort4*>(Gb);
    int beg = ptr[n], end = ptr[n + 1];
    float4 a0 = make_float4(0.f, 0.f, 0.f, 0.f), a1 = a0, a2 = a0, a3 = a0;
    int e = beg;
    for (; e + 8 <= end; e += 8) {
        uint2 e0 = eidx[e + 0], e1 = eidx[e + 1], e2 = eidx[e + 2], e3 = eidx[e + 3];
        uint2 e4 = eidx[e + 4], e5 = eidx[e + 5], e6 = eidx[e + 6], e7 = eidx[e + 7];
        ushort4 g0 = Gv[(size_t)e0.x * 32 + l];
        ushort4 g1 = Gv[(size_t)e1.x * 32 + l];
        ushort4 g2 = Gv[(size_t)e2.x * 32 + l];
        ushort4 g3 = Gv[(size_t)e3.x * 32 + l];
        ushort4 g4 = Gv[(size_t)e4.x * 32 + l];
        ushort4 g5 = Gv[(size_t)e5.x * 32 + l];
        ushort4 g6 = Gv[(size_t)e6.x * 32 + l];
        ushort4 g7 = Gv[(size_t)e7.x * 32 + l];
        fma4b(a0, __uint_as_float(e0.y), g0);
        fma4b(a1, __uint_as_float(e1.y), g1);
        fma4b(a2, __uint_as_float(e2.y), g2);
        fma4b(a3, __uint_as_float(e3.y), g3);
        fma4b(a0, __uint_as_float(e4.y), g4);
        fma4b(a1, __uint_as_float(e5.y), g5);
        fma4b(a2, __uint_as_float(e6.y), g6);
        fma4b(a3, __uint_as_float(e7.y), g7);
    }
    for (; e + 4 <= end; e += 4) {
        uint2 e0 = eidx[e + 0], e1 = eidx[e + 1], e2 = eidx[e + 2], e3 = eidx[e + 3];
        ushort4 g0 = Gv[(size_t)e0.x * 32 + l];
        ushort4 g1 = Gv[(size_t)e1.x * 32 + l];
        ushort4 g2 = Gv[(size_t)e2.x * 32 + l];
        ushort4 g3 = Gv[(size_t)e3.x * 32 + l];
        fma4b(a0, __uint_as_float(e0.y), g0);
        fma4b(a1, __uint_as_float(e1.y), g1);
        fma4b(a2, __uint_as_float(e2.y), g2);
        fma4b(a3, __uint_as_float(e3.y), g3);
    }
    for (; e < end; ++e) {
        uint2 e0 = eidx[e];
        ushort4 g = Gv[(size_t)e0.x * 32 + l];
        fma4b(a0, __uint_as_float(e0.y), g);
    }
    float4 acc;
    acc.x = (a0.x + a1.x) + (a2.x + a3.x);
    acc.y = (a0.y + a1.y) + (a2.y + a3.y);
    acc.z = (a0.z + a1.z) + (a2.z + a3.z);
    acc.w = (a0.w + a1.w) + (a2.w + a3.w);

    float di = dinv[n];
    float d2 = di * di;
    ushort4 gu = Gv[(size_t)n * 32 + l];
    float4 gs = make_float4(bf2f(gu.x), bf2f(gu.y), bf2f(gu.z), bf2f(gu.w));
    float4 b4 = reinterpret_cast<const float4*>(bias)[l];
    float4 v;
    v.x = fmaf(di, acc.x, fmaf(d2, gs.x, b4.x));
    v.y = fmaf(di, acc.y, fmaf(d2, gs.y, b4.y));
    v.z = fmaf(di, acc.z, fmaf(d2, gs.z, b4.z));
    v.w = fmaf(di, acc.w, fmaf(d2, gs.w, b4.w));
    if (relu_res) {
        float4 s4 = reinterpret_cast<const float4*>(skip)[(size_t)n * 32 + l];
        v.x = fmaxf(v.x, 0.f) + s4.x;
        v.y = fmaxf(v.y, 0.f) + s4.y;
        v.z = fmaxf(v.z, 0.f) + s4.z;
        v.w = fmaxf(v.w, 0.f) + s4.w;
    }
    reinterpret_cast<float4*>(out)[(size_t)n * 32 + l] = v;
    reinterpret_cast<ushort4*>(outb)[(size_t)n * 32 + l] =
        make_ushort4(f2bf(v.x), f2bf(v.y), f2bf(v.z), f2bf(v.w));
}

// ---------------------------------------------------------------------------
// final classifier as LDS-tiled GEMM (outs padded 40->64), fp32 in/out
__global__ __launch_bounds__(256) void k_final(const float* __restrict__ H,
                                               const float* __restrict__ Wf,
                                               const float* __restrict__ bf,
                                               float* __restrict__ out, int N) {
    __shared__ float Xs[16][68];
    __shared__ float Ws[16][64];
    int tid = threadIdx.x;
    int n0 = blockIdx.x * 64;
    int tx = tid & 15;
    int ty = tid >> 4;
    float acc[4][4] = {};
    for (int k0 = 0; k0 < DIM; k0 += 16) {
        {
            int j = tid >> 2, kq = tid & 3;
            int row = n0 + j;
            if (row >= N) row = N - 1;
            const float4 x4 = *reinterpret_cast<const float4*>(&H[(size_t)row * DIM + k0 + kq * 4]);
            Xs[kq * 4 + 0][j] = x4.x;
            Xs[kq * 4 + 1][j] = x4.y;
            Xs[kq * 4 + 2][j] = x4.z;
            Xs[kq * 4 + 3][j] = x4.w;
        }
        {
            int o = tid >> 2, kq = tid & 3;
            int om = o < NCLS ? o : o - NCLS;
            const float4 w4 = *reinterpret_cast<const float4*>(&Wf[(size_t)om * DIM + k0 + kq * 4]);
            Ws[kq * 4 + 0][o] = w4.x;
            Ws[kq * 4 + 1][o] = w4.y;
            Ws[kq * 4 + 2][o] = w4.z;
            Ws[kq * 4 + 3][o] = w4.w;
        }
        __syncthreads();
        #pragma unroll
        for (int k = 0; k < 16; ++k) {
            float4 w = *reinterpret_cast<const float4*>(&Ws[k][tx * 4]);
            float4 x = *reinterpret_cast<const float4*>(&Xs[k][ty * 4]);
            float xv[4] = {x.x, x.y, x.z, x.w};
            #pragma unroll
            for (int i = 0; i < 4; ++i) {
                acc[i][0] = fmaf(xv[i], w.x, acc[i][0]);
                acc[i][1] = fmaf(xv[i], w.y, acc[i][1]);
                acc[i][2] = fmaf(xv[i], w.z, acc[i][2]);
                acc[i][3] = fmaf(xv[i], w.w, acc[i][3]);
            }
        }
        __syncthreads();
    }
    if (tx >= 10) return;
    float4 b4 = make_float4(bf[tx * 4], bf[tx * 4 + 1], bf[tx * 4 + 2], bf[tx * 4 + 3]);
    #pragma unroll
    for (int i = 0; i < 4; ++i) {
        int row = n0 + ty * 4 + i;
        if (row < N) {
            float* op = &out[(size_t)row * NCLS + tx * 4];
            op[0] = acc[i][0] + b4.x;
            op[1] = acc[i][1] + b4.y;
            op[2] = acc[i][2] + b4.z;
            op[3] = acc[i][3] + b4.w;
        }
    }
}

// ---------------------------------------------------------------------------
extern "C" void kernel_launch(void* const* d_in, const int* in_sizes, int n_in,
                              void* d_out, int out_size, void* d_ws, size_t ws_size,
                              hipStream_t stream) {
    (void)in_sizes; (void)n_in; (void)out_size; (void)ws_size;
    const float* X  = (const float*)d_in[0];
    const int*   A  = (const int*)d_in[1];
    const float* W0 = (const float*)d_in[2];
    const float* b0 = (const float*)d_in[3];
    const float* W1 = (const float*)d_in[4];
    const float* b1 = (const float*)d_in[5];
    const float* W2 = (const float*)d_in[6];
    const float* b2 = (const float*)d_in[7];
    const float* W3 = (const float*)d_in[8];
    const float* b3 = (const float*)d_in[9];
    const float* Wf = (const float*)d_in[10];
    const float* bf = (const float*)d_in[11];
    float* out = (float*)d_out;

    char* base_ws = (char*)d_ws;
    size_t off = 0;
    auto alloc = [&](size_t bytes) -> char* {
        char* p = base_ws + off;
        off = (off + bytes + 255) & ~(size_t)255;
        return p;
    };
    float* scale_inv = (float*)alloc(4 * sizeof(float));
    int*   deg   = (int*)alloc(N_NODES_C * sizeof(int));
    int*   fill  = (int*)alloc(N_NODES_C * sizeof(int));
    int*   ptr   = (int*)alloc((N_NODES_C + 1) * sizeof(int));
    float* dinv  = (float*)alloc(N_NODES_C * sizeof(float));
    int*   part  = (int*)alloc(SCAN_NB * sizeof(int));
    int*   bbase = (int*)alloc(SCAN_NB * sizeof(int));
    uint2* eidx  = (uint2*)alloc((size_t)N_EDGES_C * sizeof(uint2));
    unsigned short* Gb = (unsigned short*)alloc((size_t)N_NODES_C * DIM * sizeof(unsigned short));
    unsigned short* Bb = (unsigned short*)alloc((size_t)N_NODES_C * DIM * sizeof(unsigned short));
    unsigned short* Wb = (unsigned short*)alloc((size_t)4 * DIM * DIM * sizeof(unsigned short));
    float* H1    = (float*)alloc((size_t)N_NODES_C * DIM * sizeof(float));
    float* H2    = (float*)alloc((size_t)N_NODES_C * DIM * sizeof(float));

    hipMemsetAsync(deg, 0, N_NODES_C * sizeof(int), stream);
    hipMemsetAsync(fill, 0, N_NODES_C * sizeof(int), stream);

    k_scales<<<4, 256, 0, stream>>>(W0, W1, W2, W3, scale_inv);
    k_w2b<<<64, 256, 0, stream>>>(W0, W1, W2, W3, Wb);
    k_f2b<<<(N_NODES_C * DIM / 4 + 255) / 256, 256, 0, stream>>>(X, Bb, N_NODES_C * DIM / 4);
    k_deg<<<(N_EDGES_C + 255) / 256, 256, 0, stream>>>(A, deg, N_EDGES_C);
    k_scan_part<<<SCAN_NB, 256, 0, stream>>>(deg, part, dinv, N_NODES_C);
    k_scan_mid<<<1, 256, 0, stream>>>(part, bbase, ptr, SCAN_NB, N_NODES_C);
    k_scan_final<<<SCAN_NB, 256, 0, stream>>>(deg, bbase, ptr, N_NODES_C);
    k_fill<<<(N_EDGES_C + 255) / 256, 256, 0, stream>>>(A, ptr, fill, dinv, eidx, N_EDGES_C);

    const int gemm_grid = (N_NODES_C + 63) / 64;
    const int agg_grid  = (N_NODES_C + 7) / 8;

    // layer 0
    k_gemm_mfma<<<gemm_grid, 256, 0, stream>>>(Bb, Wb + 0 * DIM * DIM, scale_inv + 0, Gb, N_NODES_C);
    k_agg<<<agg_grid, 256, 0, stream>>>(Gb, b0, dinv, ptr, eidx, nullptr, H1, Bb, 0, N_NODES_C);
    // layer 1
    k_gemm_mfma<<<gemm_grid, 256, 0, stream>>>(Bb, Wb + 1 * DIM * DIM, scale_inv + 1, Gb, N_NODES_C);
    k_agg<<<agg_grid, 256, 0, stream>>>(Gb, b1, dinv, ptr, eidx, H1, H2, Bb, 1, N_NODES_C);
    // layer 2
    k_gemm_mfma<<<gemm_grid, 256, 0, stream>>>(Bb, Wb + 2 * DIM * DIM, scale_inv + 2, Gb, N_NODES_C);
    k_agg<<<agg_grid, 256, 0, stream>>>(Gb, b2, dinv, ptr, eidx, H2, H1, Bb, 1, N_NODES_C);
    // layer 3
    k_gemm_mfma<<<gemm_grid, 256, 0, stream>>>(Bb, Wb + 3 * DIM * DIM, scale_inv + 3, Gb, N_NODES_C);
    k_agg<<<agg_grid, 256, 0, stream>>>(Gb, b3, dinv, ptr, eidx, H1, H2, Bb, 1, N_NODES_C);
    // final classifier
    k_final<<<(N_NODES_C + 63) / 64, 256, 0, stream>>>(H2, Wf, bf, out, N_NODES_C);
}

// Round 7
// 364.088 us; speedup vs baseline: 2.7728x; 1.0275x over previous
//
#include <hip/hip_runtime.h>

#define N_NODES_C 50000
#define N_EDGES_C 800000
#define DIM 128
#define NCLS 40
#define SCAN_NB ((N_NODES_C + 255) / 256)

typedef __attribute__((ext_vector_type(8))) short bf16x8;
typedef __attribute__((ext_vector_type(4))) float f32x4;

__device__ inline float bf2f(unsigned short u) {
    union { unsigned int i; float f; } c;
    c.i = ((unsigned int)u) << 16;
    return c.f;
}
__device__ inline unsigned short f2bf(float f) {
    union { float f; unsigned int i; } c;
    c.f = f;
    unsigned int x = c.i;
    x += 0x7fffu + ((x >> 16) & 1u);   // RNE
    return (unsigned short)(x >> 16);
}
__device__ inline void add4b(float4& a, const ushort4& u) {
    a.x += bf2f(u.x);
    a.y += bf2f(u.y);
    a.z += bf2f(u.z);
    a.w += bf2f(u.w);
}

// ---------------------------------------------------------------------------
// Frobenius-norm scales (on fp32 W, matches reference)
__global__ __launch_bounds__(256) void k_scales(const float* __restrict__ W0,
                                                const float* __restrict__ W1,
                                                const float* __restrict__ W2,
                                                const float* __restrict__ W3,
                                                float* __restrict__ scale_inv) {
    const float* W = blockIdx.x == 0 ? W0 : blockIdx.x == 1 ? W1 : blockIdx.x == 2 ? W2 : W3;
    float s = 0.f;
    for (int i = threadIdx.x; i < DIM * DIM; i += 256) {
        float v = W[i];
        s += v * v;
    }
    #pragma unroll
    for (int off = 32; off >= 1; off >>= 1) s += __shfl_down(s, off);
    __shared__ float red[4];
    int lane = threadIdx.x & 63, wid = threadIdx.x >> 6;
    if (lane == 0) red[wid] = s;
    __syncthreads();
    if (threadIdx.x == 0) {
        float tot = red[0] + red[1] + red[2] + red[3];
        scale_inv[blockIdx.x] = 1.0f / sqrtf(tot);
    }
}

// fp32 -> bf16 bulk convert (4 elems/thread)
__global__ __launch_bounds__(256) void k_f2b(const float* __restrict__ in,
                                             unsigned short* __restrict__ outb, int n4) {
    int i = blockIdx.x * 256 + threadIdx.x;
    if (i >= n4) return;
    float4 v = reinterpret_cast<const float4*>(in)[i];
    reinterpret_cast<ushort4*>(outb)[i] =
        make_ushort4(f2bf(v.x), f2bf(v.y), f2bf(v.z), f2bf(v.w));
}

// weights fp32 -> bf16 (4 matrices into one buffer)
__global__ __launch_bounds__(256) void k_w2b(const float* __restrict__ W0,
                                             const float* __restrict__ W1,
                                             const float* __restrict__ W2,
                                             const float* __restrict__ W3,
                                             unsigned short* __restrict__ Wb) {
    int m = blockIdx.x >> 4;
    int idx = (blockIdx.x & 15) * 256 + threadIdx.x;   // 0..4095 float4s
    const float* W = m == 0 ? W0 : m == 1 ? W1 : m == 2 ? W2 : W3;
    float4 v = reinterpret_cast<const float4*>(W)[idx];
    reinterpret_cast<ushort4*>(Wb + (size_t)m * DIM * DIM)[idx] =
        make_ushort4(f2bf(v.x), f2bf(v.y), f2bf(v.z), f2bf(v.w));
}

// ---------------------------------------------------------------------------
__global__ void k_deg(const int* __restrict__ A, int* __restrict__ cnt, int E) {
    int e = blockIdx.x * 256 + threadIdx.x;
    if (e >= E) return;
    atomicAdd(&cnt[A[E + e]], 1);
}

__global__ __launch_bounds__(256) void k_scan_part(const int* __restrict__ cnt,
                                                   int* __restrict__ partial,
                                                   float* __restrict__ dinv, int n) {
    int idx = blockIdx.x * 256 + threadIdx.x;
    int v = (idx < n) ? cnt[idx] : 0;
    if (idx < n) dinv[idx] = rsqrtf((float)v + 1.0f);
    int s = v;
    #pragma unroll
    for (int off = 32; off >= 1; off >>= 1) s += __shfl_down(s, off);
    __shared__ int red[4];
    int lane = threadIdx.x & 63, wid = threadIdx.x >> 6;
    if (lane == 0) red[wid] = s;
    __syncthreads();
    if (threadIdx.x == 0) partial[blockIdx.x] = red[0] + red[1] + red[2] + red[3];
}

__global__ __launch_bounds__(256) void k_scan_mid(const int* __restrict__ partial,
                                                  int* __restrict__ base,
                                                  int* __restrict__ ptr, int nb, int n) {
    int tid = threadIdx.x;
    int v = (tid < nb) ? partial[tid] : 0;
    int lane = tid & 63, wid = tid >> 6;
    int sc = v;
    #pragma unroll
    for (int off = 1; off < 64; off <<= 1) {
        int t = __shfl_up(sc, off);
        if (lane >= off) sc += t;
    }
    __shared__ int wsum[4], wpre[4];
    if (lane == 63) wsum[wid] = sc;
    __syncthreads();
    if (tid == 0) {
        int acc = 0;
        #pragma unroll
        for (int w = 0; w < 4; ++w) { wpre[w] = acc; acc += wsum[w]; }
    }
    __syncthreads();
    int excl = wpre[wid] + sc - v;
    if (tid < nb) base[tid] = excl;
    if (tid == 255) ptr[n] = wpre[3] + sc;
}

__global__ __launch_bounds__(256) void k_scan_final(const int* __restrict__ cnt,
                                                    const int* __restrict__ base,
                                                    int* __restrict__ ptr, int n) {
    int idx = blockIdx.x * 256 + threadIdx.x;
    int v = (idx < n) ? cnt[idx] : 0;
    int tid = threadIdx.x, lane = tid & 63, wid = tid >> 6;
    int sc = v;
    #pragma unroll
    for (int off = 1; off < 64; off <<= 1) {
        int t = __shfl_up(sc, off);
        if (lane >= off) sc += t;
    }
    __shared__ int wsum[4], wpre[4];
    if (lane == 63) wsum[wid] = sc;
    __syncthreads();
    if (tid == 0) {
        int acc = 0;
        #pragma unroll
        for (int w = 0; w < 4; ++w) { wpre[w] = acc; acc += wsum[w]; }
    }
    __syncthreads();
    if (idx < n) ptr[idx] = base[blockIdx.x] + wpre[wid] + sc - v;
}

// fill CSR: one 4B write per edge (src index only; weights folded into G)
__global__ void k_fill(const int* __restrict__ A, const int* __restrict__ ptr,
                       int* __restrict__ fill, int* __restrict__ esrc, int E) {
    int e = blockIdx.x * 256 + threadIdx.x;
    if (e >= E) return;
    int s = A[e];
    int d = A[E + e];
    int pos = ptr[d] + atomicAdd(&fill[d], 1);
    esrc[pos] = s;
}

// ---------------------------------------------------------------------------
// bf16 MFMA GEMM with dinv-prescale epilogue:
//   Gb[n][o] = bf16(dinv[n] * scale * sum_k Xb[n][k] * Wb[o][k])
// block = 256 thr (4 waves); wave w: rows n0+w*16..+15, all 128 cols.
__global__ __launch_bounds__(256) void k_gemm_mfma(const unsigned short* __restrict__ Xb,
                                                   const unsigned short* __restrict__ Wb,
                                                   const float* __restrict__ scale_ptr,
                                                   const float* __restrict__ dinv,
                                                   unsigned short* __restrict__ Gb, int N) {
    int tid = threadIdx.x;
    int w = tid >> 6;
    int l = tid & 63;
    int l15 = l & 15;
    int lg = l >> 4;
    int arow = blockIdx.x * 64 + w * 16 + l15;
    if (arow >= N) arow = N - 1;
    float scale = scale_ptr[0];

    f32x4 acc[8];
    #pragma unroll
    for (int ct = 0; ct < 8; ++ct) acc[ct] = f32x4{0.f, 0.f, 0.f, 0.f};

    #pragma unroll
    for (int kc = 0; kc < 4; ++kc) {
        int ko = kc * 32 + lg * 8;
        bf16x8 a = *reinterpret_cast<const bf16x8*>(&Xb[(size_t)arow * DIM + ko]);
        #pragma unroll
        for (int ct = 0; ct < 8; ++ct) {
            bf16x8 b = *reinterpret_cast<const bf16x8*>(&Wb[(size_t)(ct * 16 + l15) * DIM + ko]);
            acc[ct] = __builtin_amdgcn_mfma_f32_16x16x32_bf16(a, b, acc[ct], 0, 0, 0);
        }
    }
    int outrow0 = blockIdx.x * 64 + w * 16 + lg * 4;
    #pragma unroll
    for (int r = 0; r < 4; ++r) {
        int row = outrow0 + r;
        if (row < N) {
            float dv = dinv[row] * scale;
            #pragma unroll
            for (int ct = 0; ct < 8; ++ct)
                Gb[(size_t)row * DIM + ct * 16 + l15] = f2bf(acc[ct][r] * dv);
        }
    }
}

// ---------------------------------------------------------------------------
// aggregation over prescaled bf16 G: out = dinv[n]*(sum_edges G[src] + G[n]) + b
// (+ relu + residual). fp32 accum, bf16 in/out. 8 nodes/256-block, 32 lanes/node.
__global__ __launch_bounds__(256) void k_agg(const unsigned short* __restrict__ Gb,
                                             const float* __restrict__ bias,
                                             const float* __restrict__ dinv,
                                             const int* __restrict__ ptr,
                                             const int* __restrict__ esrc,
                                             const unsigned short* __restrict__ skipb,
                                             unsigned short* __restrict__ outb,
                                             int relu_res, int N) {
    int n = blockIdx.x * 8 + (threadIdx.x >> 5);
    if (n >= N) return;
    int l = threadIdx.x & 31;
    const ushort4* __restrict__ Gv = reinterpret_cast<const ushort4*>(Gb);
    int beg = ptr[n], end = ptr[n + 1];
    float4 a0 = make_float4(0.f, 0.f, 0.f, 0.f), a1 = a0, a2 = a0, a3 = a0;
    int e = beg;
    for (; e + 8 <= end; e += 8) {
        int s0 = esrc[e + 0], s1 = esrc[e + 1], s2 = esrc[e + 2], s3 = esrc[e + 3];
        int s4 = esrc[e + 4], s5 = esrc[e + 5], s6 = esrc[e + 6], s7 = esrc[e + 7];
        ushort4 g0 = Gv[(size_t)s0 * 32 + l];
        ushort4 g1 = Gv[(size_t)s1 * 32 + l];
        ushort4 g2 = Gv[(size_t)s2 * 32 + l];
        ushort4 g3 = Gv[(size_t)s3 * 32 + l];
        ushort4 g4 = Gv[(size_t)s4 * 32 + l];
        ushort4 g5 = Gv[(size_t)s5 * 32 + l];
        ushort4 g6 = Gv[(size_t)s6 * 32 + l];
        ushort4 g7 = Gv[(size_t)s7 * 32 + l];
        add4b(a0, g0);
        add4b(a1, g1);
        add4b(a2, g2);
        add4b(a3, g3);
        add4b(a0, g4);
        add4b(a1, g5);
        add4b(a2, g6);
        add4b(a3, g7);
    }
    for (; e + 4 <= end; e += 4) {
        int s0 = esrc[e + 0], s1 = esrc[e + 1], s2 = esrc[e + 2], s3 = esrc[e + 3];
        ushort4 g0 = Gv[(size_t)s0 * 32 + l];
        ushort4 g1 = Gv[(size_t)s1 * 32 + l];
        ushort4 g2 = Gv[(size_t)s2 * 32 + l];
        ushort4 g3 = Gv[(size_t)s3 * 32 + l];
        add4b(a0, g0);
        add4b(a1, g1);
        add4b(a2, g2);
        add4b(a3, g3);
    }
    for (; e < end; ++e) {
        ushort4 g = Gv[(size_t)esrc[e] * 32 + l];
        add4b(a0, g);
    }
    float4 acc;
    acc.x = (a0.x + a1.x) + (a2.x + a3.x);
    acc.y = (a0.y + a1.y) + (a2.y + a3.y);
    acc.z = (a0.z + a1.z) + (a2.z + a3.z);
    acc.w = (a0.w + a1.w) + (a2.w + a3.w);

    float di = dinv[n];
    ushort4 gu = Gv[(size_t)n * 32 + l];
    float4 b4 = reinterpret_cast<const float4*>(bias)[l];
    float4 v;
    v.x = fmaf(di, acc.x + bf2f(gu.x), b4.x);
    v.y = fmaf(di, acc.y + bf2f(gu.y), b4.y);
    v.z = fmaf(di, acc.z + bf2f(gu.z), b4.z);
    v.w = fmaf(di, acc.w + bf2f(gu.w), b4.w);
    if (relu_res) {
        ushort4 su = reinterpret_cast<const ushort4*>(skipb)[(size_t)n * 32 + l];
        v.x = fmaxf(v.x, 0.f) + bf2f(su.x);
        v.y = fmaxf(v.y, 0.f) + bf2f(su.y);
        v.z = fmaxf(v.z, 0.f) + bf2f(su.z);
        v.w = fmaxf(v.w, 0.f) + bf2f(su.w);
    }
    reinterpret_cast<ushort4*>(outb)[(size_t)n * 32 + l] =
        make_ushort4(f2bf(v.x), f2bf(v.y), f2bf(v.z), f2bf(v.w));
}

// ---------------------------------------------------------------------------
// final classifier, bf16 H input, fp32 Wf/compute/output (outs padded 40->64)
__global__ __launch_bounds__(256) void k_final(const unsigned short* __restrict__ Hb,
                                               const float* __restrict__ Wf,
                                               const float* __restrict__ bf,
                                               float* __restrict__ out, int N) {
    __shared__ float Xs[16][68];
    __shared__ float Ws[16][64];
    int tid = threadIdx.x;
    int n0 = blockIdx.x * 64;
    int tx = tid & 15;
    int ty = tid >> 4;
    float acc[4][4] = {};
    for (int k0 = 0; k0 < DIM; k0 += 16) {
        {
            int j = tid >> 2, kq = tid & 3;
            int row = n0 + j;
            if (row >= N) row = N - 1;
            ushort4 x4 = *reinterpret_cast<const ushort4*>(&Hb[(size_t)row * DIM + k0 + kq * 4]);
            Xs[kq * 4 + 0][j] = bf2f(x4.x);
            Xs[kq * 4 + 1][j] = bf2f(x4.y);
            Xs[kq * 4 + 2][j] = bf2f(x4.z);
            Xs[kq * 4 + 3][j] = bf2f(x4.w);
        }
        {
            int o = tid >> 2, kq = tid & 3;
            int om = o < NCLS ? o : o - NCLS;
            const float4 w4 = *reinterpret_cast<const float4*>(&Wf[(size_t)om * DIM + k0 + kq * 4]);
            Ws[kq * 4 + 0][o] = w4.x;
            Ws[kq * 4 + 1][o] = w4.y;
            Ws[kq * 4 + 2][o] = w4.z;
            Ws[kq * 4 + 3][o] = w4.w;
        }
        __syncthreads();
        #pragma unroll
        for (int k = 0; k < 16; ++k) {
            float4 w = *reinterpret_cast<const float4*>(&Ws[k][tx * 4]);
            float4 x = *reinterpret_cast<const float4*>(&Xs[k][ty * 4]);
            float xv[4] = {x.x, x.y, x.z, x.w};
            #pragma unroll
            for (int i = 0; i < 4; ++i) {
                acc[i][0] = fmaf(xv[i], w.x, acc[i][0]);
                acc[i][1] = fmaf(xv[i], w.y, acc[i][1]);
                acc[i][2] = fmaf(xv[i], w.z, acc[i][2]);
                acc[i][3] = fmaf(xv[i], w.w, acc[i][3]);
            }
        }
        __syncthreads();
    }
    if (tx >= 10) return;
    float4 b4 = make_float4(bf[tx * 4], bf[tx * 4 + 1], bf[tx * 4 + 2], bf[tx * 4 + 3]);
    #pragma unroll
    for (int i = 0; i < 4; ++i) {
        int row = n0 + ty * 4 + i;
        if (row < N) {
            float* op = &out[(size_t)row * NCLS + tx * 4];
            op[0] = acc[i][0] + b4.x;
            op[1] = acc[i][1] + b4.y;
            op[2] = acc[i][2] + b4.z;
            op[3] = acc[i][3] + b4.w;
        }
    }
}

// ---------------------------------------------------------------------------
extern "C" void kernel_launch(void* const* d_in, const int* in_sizes, int n_in,
                              void* d_out, int out_size, void* d_ws, size_t ws_size,
                              hipStream_t stream) {
    (void)in_sizes; (void)n_in; (void)out_size; (void)ws_size;
    const float* X  = (const float*)d_in[0];
    const int*   A  = (const int*)d_in[1];
    const float* W0 = (const float*)d_in[2];
    const float* b0 = (const float*)d_in[3];
    const float* W1 = (const float*)d_in[4];
    const float* b1 = (const float*)d_in[5];
    const float* W2 = (const float*)d_in[6];
    const float* b2 = (const float*)d_in[7];
    const float* W3 = (const float*)d_in[8];
    const float* b3 = (const float*)d_in[9];
    const float* Wf = (const float*)d_in[10];
    const float* bf = (const float*)d_in[11];
    float* out = (float*)d_out;

    char* base_ws = (char*)d_ws;
    size_t off = 0;
    auto alloc = [&](size_t bytes) -> char* {
        char* p = base_ws + off;
        off = (off + bytes + 255) & ~(size_t)255;
        return p;
    };
    float* scale_inv = (float*)alloc(4 * sizeof(float));
    int*   deg   = (int*)alloc(N_NODES_C * sizeof(int));
    int*   fill  = (int*)alloc(N_NODES_C * sizeof(int));
    int*   ptr   = (int*)alloc((N_NODES_C + 1) * sizeof(int));
    float* dinv  = (float*)alloc(N_NODES_C * sizeof(float));
    int*   part  = (int*)alloc(SCAN_NB * sizeof(int));
    int*   bbase = (int*)alloc(SCAN_NB * sizeof(int));
    int*   esrc  = (int*)alloc((size_t)N_EDGES_C * sizeof(int));
    unsigned short* Gb  = (unsigned short*)alloc((size_t)N_NODES_C * DIM * sizeof(unsigned short));
    unsigned short* Xb  = (unsigned short*)alloc((size_t)N_NODES_C * DIM * sizeof(unsigned short));
    unsigned short* Hb1 = (unsigned short*)alloc((size_t)N_NODES_C * DIM * sizeof(unsigned short));
    unsigned short* Hb2 = (unsigned short*)alloc((size_t)N_NODES_C * DIM * sizeof(unsigned short));
    unsigned short* Wb  = (unsigned short*)alloc((size_t)4 * DIM * DIM * sizeof(unsigned short));

    hipMemsetAsync(deg, 0, N_NODES_C * sizeof(int), stream);
    hipMemsetAsync(fill, 0, N_NODES_C * sizeof(int), stream);

    k_scales<<<4, 256, 0, stream>>>(W0, W1, W2, W3, scale_inv);
    k_w2b<<<64, 256, 0, stream>>>(W0, W1, W2, W3, Wb);
    k_f2b<<<(N_NODES_C * DIM / 4 + 255) / 256, 256, 0, stream>>>(X, Xb, N_NODES_C * DIM / 4);
    k_deg<<<(N_EDGES_C + 255) / 256, 256, 0, stream>>>(A, deg, N_EDGES_C);
    k_scan_part<<<SCAN_NB, 256, 0, stream>>>(deg, part, dinv, N_NODES_C);
    k_scan_mid<<<1, 256, 0, stream>>>(part, bbase, ptr, SCAN_NB, N_NODES_C);
    k_scan_final<<<SCAN_NB, 256, 0, stream>>>(deg, bbase, ptr, N_NODES_C);
    k_fill<<<(N_EDGES_C + 255) / 256, 256, 0, stream>>>(A, ptr, fill, esrc, N_EDGES_C);

    const int gemm_grid = (N_NODES_C + 63) / 64;
    const int agg_grid  = (N_NODES_C + 7) / 8;

    // layer 0
    k_gemm_mfma<<<gemm_grid, 256, 0, stream>>>(Xb, Wb + 0 * DIM * DIM, scale_inv + 0, dinv, Gb, N_NODES_C);
    k_agg<<<agg_grid, 256, 0, stream>>>(Gb, b0, dinv, ptr, esrc, nullptr, Hb1, 0, N_NODES_C);
    // layer 1
    k_gemm_mfma<<<gemm_grid, 256, 0, stream>>>(Hb1, Wb + 1 * DIM * DIM, scale_inv + 1, dinv, Gb, N_NODES_C);
    k_agg<<<agg_grid, 256, 0, stream>>>(Gb, b1, dinv, ptr, esrc, Hb1, Hb2, 1, N_NODES_C);
    // layer 2
    k_gemm_mfma<<<gemm_grid, 256, 0, stream>>>(Hb2, Wb + 2 * DIM * DIM, scale_inv + 2, dinv, Gb, N_NODES_C);
    k_agg<<<agg_grid, 256, 0, stream>>>(Gb, b2, dinv, ptr, esrc, Hb2, Hb1, 1, N_NODES_C);
    // layer 3
    k_gemm_mfma<<<gemm_grid, 256, 0, stream>>>(Hb1, Wb + 3 * DIM * DIM, scale_inv + 3, dinv, Gb, N_NODES_C);
    k_agg<<<agg_grid, 256, 0, stream>>>(Gb, b3, dinv, ptr, esrc, Hb1, Hb2, 1, N_NODES_C);
    // final classifier
    k_final<<<(N_NODES_C + 63) / 64, 256, 0, stream>>>(Hb2, Wf, bf, out, N_NODES_C);
}

// Round 8
// 348.663 us; speedup vs baseline: 2.8955x; 1.0442x over previous
//
#include <hip/hip_runtime.h>

#define N_NODES_C 50000
#define N_EDGES_C 800000
#define DIM 128
#define NCLS 40
#define SCAN_NB ((N_NODES_C + 255) / 256)      // 196
#define F2B_NB ((N_NODES_C * DIM / 4) / 256)   // 6250 (exact)

typedef __attribute__((ext_vector_type(8))) short bf16x8;
typedef __attribute__((ext_vector_type(4))) float f32x4;

__device__ inline float bf2f(unsigned short u) {
    union { unsigned int i; float f; } c;
    c.i = ((unsigned int)u) << 16;
    return c.f;
}
__device__ inline unsigned short f2bf(float f) {
    union { float f; unsigned int i; } c;
    c.f = f;
    unsigned int x = c.i;
    x += 0x7fffu + ((x >> 16) & 1u);   // RNE
    return (unsigned short)(x >> 16);
}
__device__ inline void add4b(float4& a, const ushort4& u) {
    a.x += bf2f(u.x);
    a.y += bf2f(u.y);
    a.z += bf2f(u.z);
    a.w += bf2f(u.w);
}

// ---------------------------------------------------------------------------
// fused preprocessing: [0,F2B_NB) X->bf16 ; [F2B_NB,+64) W->bf16 ; last 4: scales
__global__ __launch_bounds__(256) void k_pre(const float* __restrict__ X,
                                             const float* __restrict__ W0,
                                             const float* __restrict__ W1,
                                             const float* __restrict__ W2,
                                             const float* __restrict__ W3,
                                             unsigned short* __restrict__ Xb,
                                             unsigned short* __restrict__ Wb,
                                             float* __restrict__ scale_inv) {
    int b = blockIdx.x;
    if (b < F2B_NB) {
        int i = b * 256 + threadIdx.x;
        float4 v = reinterpret_cast<const float4*>(X)[i];
        reinterpret_cast<ushort4*>(Xb)[i] =
            make_ushort4(f2bf(v.x), f2bf(v.y), f2bf(v.z), f2bf(v.w));
        return;
    }
    b -= F2B_NB;
    if (b < 64) {
        int m = b >> 4;
        int idx = (b & 15) * 256 + threadIdx.x;
        const float* W = m == 0 ? W0 : m == 1 ? W1 : m == 2 ? W2 : W3;
        float4 v = reinterpret_cast<const float4*>(W)[idx];
        reinterpret_cast<ushort4*>(Wb + (size_t)m * DIM * DIM)[idx] =
            make_ushort4(f2bf(v.x), f2bf(v.y), f2bf(v.z), f2bf(v.w));
        return;
    }
    b -= 64;
    const float* W = b == 0 ? W0 : b == 1 ? W1 : b == 2 ? W2 : W3;
    float s = 0.f;
    for (int i = threadIdx.x; i < DIM * DIM; i += 256) {
        float v = W[i];
        s += v * v;
    }
    #pragma unroll
    for (int off = 32; off >= 1; off >>= 1) s += __shfl_down(s, off);
    __shared__ float red[4];
    int lane = threadIdx.x & 63, wid = threadIdx.x >> 6;
    if (lane == 0) red[wid] = s;
    __syncthreads();
    if (threadIdx.x == 0) {
        float tot = red[0] + red[1] + red[2] + red[3];
        scale_inv[b] = 1.0f / sqrtf(tot);
    }
}

// ---------------------------------------------------------------------------
__global__ void k_deg(const int* __restrict__ A, int* __restrict__ cnt, int E) {
    int e = blockIdx.x * 256 + threadIdx.x;
    if (e >= E) return;
    atomicAdd(&cnt[A[E + e]], 1);
}

// scan phase 1: per-block sums (coalesced), dinv, and fill=0 init
__global__ __launch_bounds__(256) void k_scan_part(const int* __restrict__ cnt,
                                                   int* __restrict__ partial,
                                                   float* __restrict__ dinv,
                                                   int* __restrict__ fill, int n) {
    int idx = blockIdx.x * 256 + threadIdx.x;
    int v = (idx < n) ? cnt[idx] : 0;
    if (idx < n) {
        dinv[idx] = rsqrtf((float)v + 1.0f);
        fill[idx] = 0;
    }
    int s = v;
    #pragma unroll
    for (int off = 32; off >= 1; off >>= 1) s += __shfl_down(s, off);
    __shared__ int red[4];
    int lane = threadIdx.x & 63, wid = threadIdx.x >> 6;
    if (lane == 0) red[wid] = s;
    __syncthreads();
    if (threadIdx.x == 0) partial[blockIdx.x] = red[0] + red[1] + red[2] + red[3];
}

// scan phase 2 (fused): each block computes its own base from partials, then
// per-element exclusive scan -> ptr.  block 0 thread 0 writes ptr[n]=total.
__global__ __launch_bounds__(256) void k_scan_final(const int* __restrict__ cnt,
                                                    const int* __restrict__ partial,
                                                    int* __restrict__ ptr, int n, int nb) {
    int tid = threadIdx.x, bid = blockIdx.x;
    int lane = tid & 63, wid = tid >> 6;
    // base (sum of partials < bid) and total (sum of all partials)
    int pv = (tid < nb) ? partial[tid] : 0;
    int vb = (tid < bid) ? pv : 0;
    int s1 = vb, s2 = pv;
    #pragma unroll
    for (int off = 32; off >= 1; off >>= 1) {
        s1 += __shfl_down(s1, off);
        s2 += __shfl_down(s2, off);
    }
    __shared__ int r1[4], r2[4];
    if (lane == 0) { r1[wid] = s1; r2[wid] = s2; }
    __syncthreads();
    __shared__ int sbase, stot;
    if (tid == 0) {
        sbase = r1[0] + r1[1] + r1[2] + r1[3];
        stot  = r2[0] + r2[1] + r2[2] + r2[3];
    }
    __syncthreads();
    // per-element scan
    int idx = bid * 256 + tid;
    int v = (idx < n) ? cnt[idx] : 0;
    int sc = v;
    #pragma unroll
    for (int off = 1; off < 64; off <<= 1) {
        int t = __shfl_up(sc, off);
        if (lane >= off) sc += t;
    }
    __shared__ int wsum[4], wpre[4];
    if (lane == 63) wsum[wid] = sc;
    __syncthreads();
    if (tid == 0) {
        int acc = 0;
        #pragma unroll
        for (int w = 0; w < 4; ++w) { wpre[w] = acc; acc += wsum[w]; }
    }
    __syncthreads();
    if (idx < n) ptr[idx] = sbase + wpre[wid] + sc - v;
    if (bid == 0 && tid == 0) ptr[n] = stot;
}

// fill CSR: one 2B write per edge (src fits ushort: N_NODES < 65536)
__global__ void k_fill(const int* __restrict__ A, const int* __restrict__ ptr,
                       int* __restrict__ fill, unsigned short* __restrict__ esrc, int E) {
    int e = blockIdx.x * 256 + threadIdx.x;
    if (e >= E) return;
    int s = A[e];
    int d = A[E + e];
    int pos = ptr[d] + atomicAdd(&fill[d], 1);
    esrc[pos] = (unsigned short)s;
}

// ---------------------------------------------------------------------------
// bf16 MFMA GEMM with dinv-prescale epilogue:
//   Gb[n][o] = bf16(dinv[n] * scale * sum_k Xb[n][k] * Wb[o][k])
__global__ __launch_bounds__(256) void k_gemm_mfma(const unsigned short* __restrict__ Xb,
                                                   const unsigned short* __restrict__ Wb,
                                                   const float* __restrict__ scale_ptr,
                                                   const float* __restrict__ dinv,
                                                   unsigned short* __restrict__ Gb, int N) {
    int tid = threadIdx.x;
    int w = tid >> 6;
    int l = tid & 63;
    int l15 = l & 15;
    int lg = l >> 4;
    int arow = blockIdx.x * 64 + w * 16 + l15;
    if (arow >= N) arow = N - 1;
    float scale = scale_ptr[0];

    f32x4 acc[8];
    #pragma unroll
    for (int ct = 0; ct < 8; ++ct) acc[ct] = f32x4{0.f, 0.f, 0.f, 0.f};

    #pragma unroll
    for (int kc = 0; kc < 4; ++kc) {
        int ko = kc * 32 + lg * 8;
        bf16x8 a = *reinterpret_cast<const bf16x8*>(&Xb[(size_t)arow * DIM + ko]);
        #pragma unroll
        for (int ct = 0; ct < 8; ++ct) {
            bf16x8 b = *reinterpret_cast<const bf16x8*>(&Wb[(size_t)(ct * 16 + l15) * DIM + ko]);
            acc[ct] = __builtin_amdgcn_mfma_f32_16x16x32_bf16(a, b, acc[ct], 0, 0, 0);
        }
    }
    int outrow0 = blockIdx.x * 64 + w * 16 + lg * 4;
    #pragma unroll
    for (int r = 0; r < 4; ++r) {
        int row = outrow0 + r;
        if (row < N) {
            float dv = dinv[row] * scale;
            #pragma unroll
            for (int ct = 0; ct < 8; ++ct)
                Gb[(size_t)row * DIM + ct * 16 + l15] = f2bf(acc[ct][r] * dv);
        }
    }
}

// ---------------------------------------------------------------------------
// aggregation over prescaled bf16 G: out = dinv[n]*(sum_edges G[src] + G[n]) + b
// (+ relu + residual). fp32 accum, bf16 in/out.
__global__ __launch_bounds__(256) void k_agg(const unsigned short* __restrict__ Gb,
                                             const float* __restrict__ bias,
                                             const float* __restrict__ dinv,
                                             const int* __restrict__ ptr,
                                             const unsigned short* __restrict__ esrc,
                                             const unsigned short* __restrict__ skipb,
                                             unsigned short* __restrict__ outb,
                                             int relu_res, int N) {
    int n = blockIdx.x * 8 + (threadIdx.x >> 5);
    if (n >= N) return;
    int l = threadIdx.x & 31;
    const ushort4* __restrict__ Gv = reinterpret_cast<const ushort4*>(Gb);
    int beg = ptr[n], end = ptr[n + 1];
    float4 a0 = make_float4(0.f, 0.f, 0.f, 0.f), a1 = a0, a2 = a0, a3 = a0;
    int e = beg;
    for (; e + 8 <= end; e += 8) {
        int s0 = esrc[e + 0], s1 = esrc[e + 1], s2 = esrc[e + 2], s3 = esrc[e + 3];
        int s4 = esrc[e + 4], s5 = esrc[e + 5], s6 = esrc[e + 6], s7 = esrc[e + 7];
        ushort4 g0 = Gv[(size_t)s0 * 32 + l];
        ushort4 g1 = Gv[(size_t)s1 * 32 + l];
        ushort4 g2 = Gv[(size_t)s2 * 32 + l];
        ushort4 g3 = Gv[(size_t)s3 * 32 + l];
        ushort4 g4 = Gv[(size_t)s4 * 32 + l];
        ushort4 g5 = Gv[(size_t)s5 * 32 + l];
        ushort4 g6 = Gv[(size_t)s6 * 32 + l];
        ushort4 g7 = Gv[(size_t)s7 * 32 + l];
        add4b(a0, g0);
        add4b(a1, g1);
        add4b(a2, g2);
        add4b(a3, g3);
        add4b(a0, g4);
        add4b(a1, g5);
        add4b(a2, g6);
        add4b(a3, g7);
    }
    for (; e + 4 <= end; e += 4) {
        int s0 = esrc[e + 0], s1 = esrc[e + 1], s2 = esrc[e + 2], s3 = esrc[e + 3];
        ushort4 g0 = Gv[(size_t)s0 * 32 + l];
        ushort4 g1 = Gv[(size_t)s1 * 32 + l];
        ushort4 g2 = Gv[(size_t)s2 * 32 + l];
        ushort4 g3 = Gv[(size_t)s3 * 32 + l];
        add4b(a0, g0);
        add4b(a1, g1);
        add4b(a2, g2);
        add4b(a3, g3);
    }
    for (; e < end; ++e) {
        ushort4 g = Gv[(size_t)esrc[e] * 32 + l];
        add4b(a0, g);
    }
    float4 acc;
    acc.x = (a0.x + a1.x) + (a2.x + a3.x);
    acc.y = (a0.y + a1.y) + (a2.y + a3.y);
    acc.z = (a0.z + a1.z) + (a2.z + a3.z);
    acc.w = (a0.w + a1.w) + (a2.w + a3.w);

    float di = dinv[n];
    ushort4 gu = Gv[(size_t)n * 32 + l];
    float4 b4 = reinterpret_cast<const float4*>(bias)[l];
    float4 v;
    v.x = fmaf(di, acc.x + bf2f(gu.x), b4.x);
    v.y = fmaf(di, acc.y + bf2f(gu.y), b4.y);
    v.z = fmaf(di, acc.z + bf2f(gu.z), b4.z);
    v.w = fmaf(di, acc.w + bf2f(gu.w), b4.w);
    if (relu_res) {
        ushort4 su = reinterpret_cast<const ushort4*>(skipb)[(size_t)n * 32 + l];
        v.x = fmaxf(v.x, 0.f) + bf2f(su.x);
        v.y = fmaxf(v.y, 0.f) + bf2f(su.y);
        v.z = fmaxf(v.z, 0.f) + bf2f(su.z);
        v.w = fmaxf(v.w, 0.f) + bf2f(su.w);
    }
    reinterpret_cast<ushort4*>(outb)[(size_t)n * 32 + l] =
        make_ushort4(f2bf(v.x), f2bf(v.y), f2bf(v.z), f2bf(v.w));
}

// ---------------------------------------------------------------------------
// final classifier, bf16 H input, fp32 Wf/compute/output (outs padded 40->64)
__global__ __launch_bounds__(256) void k_final(const unsigned short* __restrict__ Hb,
                                               const float* __restrict__ Wf,
                                               const float* __restrict__ bf,
                                               float* __restrict__ out, int N) {
    __shared__ float Xs[16][68];
    __shared__ float Ws[16][64];
    int tid = threadIdx.x;
    int n0 = blockIdx.x * 64;
    int tx = tid & 15;
    int ty = tid >> 4;
    float acc[4][4] = {};
    for (int k0 = 0; k0 < DIM; k0 += 16) {
        {
            int j = tid >> 2, kq = tid & 3;
            int row = n0 + j;
            if (row >= N) row = N - 1;
            ushort4 x4 = *reinterpret_cast<const ushort4*>(&Hb[(size_t)row * DIM + k0 + kq * 4]);
            Xs[kq * 4 + 0][j] = bf2f(x4.x);
            Xs[kq * 4 + 1][j] = bf2f(x4.y);
            Xs[kq * 4 + 2][j] = bf2f(x4.z);
            Xs[kq * 4 + 3][j] = bf2f(x4.w);
        }
        {
            int o = tid >> 2, kq = tid & 3;
            int om = o < NCLS ? o : o - NCLS;
            const float4 w4 = *reinterpret_cast<const float4*>(&Wf[(size_t)om * DIM + k0 + kq * 4]);
            Ws[kq * 4 + 0][o] = w4.x;
            Ws[kq * 4 + 1][o] = w4.y;
            Ws[kq * 4 + 2][o] = w4.z;
            Ws[kq * 4 + 3][o] = w4.w;
        }
        __syncthreads();
        #pragma unroll
        for (int k = 0; k < 16; ++k) {
            float4 w = *reinterpret_cast<const float4*>(&Ws[k][tx * 4]);
            float4 x = *reinterpret_cast<const float4*>(&Xs[k][ty * 4]);
            float xv[4] = {x.x, x.y, x.z, x.w};
            #pragma unroll
            for (int i = 0; i < 4; ++i) {
                acc[i][0] = fmaf(xv[i], w.x, acc[i][0]);
                acc[i][1] = fmaf(xv[i], w.y, acc[i][1]);
                acc[i][2] = fmaf(xv[i], w.z, acc[i][2]);
                acc[i][3] = fmaf(xv[i], w.w, acc[i][3]);
            }
        }
        __syncthreads();
    }
    if (tx >= 10) return;
    float4 b4 = make_float4(bf[tx * 4], bf[tx * 4 + 1], bf[tx * 4 + 2], bf[tx * 4 + 3]);
    #pragma unroll
    for (int i = 0; i < 4; ++i) {
        int row = n0 + ty * 4 + i;
        if (row < N) {
            float* op = &out[(size_t)row * NCLS + tx * 4];
            op[0] = acc[i][0] + b4.x;
            op[1] = acc[i][1] + b4.y;
            op[2] = acc[i][2] + b4.z;
            op[3] = acc[i][3] + b4.w;
        }
    }
}

// ---------------------------------------------------------------------------
extern "C" void kernel_launch(void* const* d_in, const int* in_sizes, int n_in,
                              void* d_out, int out_size, void* d_ws, size_t ws_size,
                              hipStream_t stream) {
    (void)in_sizes; (void)n_in; (void)out_size; (void)ws_size;
    const float* X  = (const float*)d_in[0];
    const int*   A  = (const int*)d_in[1];
    const float* W0 = (const float*)d_in[2];
    const float* b0 = (const float*)d_in[3];
    const float* W1 = (const float*)d_in[4];
    const float* b1 = (const float*)d_in[5];
    const float* W2 = (const float*)d_in[6];
    const float* b2 = (const float*)d_in[7];
    const float* W3 = (const float*)d_in[8];
    const float* b3 = (const float*)d_in[9];
    const float* Wf = (const float*)d_in[10];
    const float* bf = (const float*)d_in[11];
    float* out = (float*)d_out;

    char* base_ws = (char*)d_ws;
    size_t off = 0;
    auto alloc = [&](size_t bytes) -> char* {
        char* p = base_ws + off;
        off = (off + bytes + 255) & ~(size_t)255;
        return p;
    };
    float* scale_inv = (float*)alloc(4 * sizeof(float));
    int*   deg   = (int*)alloc(N_NODES_C * sizeof(int));
    int*   fill  = (int*)alloc(N_NODES_C * sizeof(int));
    int*   ptr   = (int*)alloc((N_NODES_C + 1) * sizeof(int));
    float* dinv  = (float*)alloc(N_NODES_C * sizeof(float));
    int*   part  = (int*)alloc(SCAN_NB * sizeof(int));
    unsigned short* esrc = (unsigned short*)alloc((size_t)N_EDGES_C * sizeof(unsigned short));
    unsigned short* Gb  = (unsigned short*)alloc((size_t)N_NODES_C * DIM * sizeof(unsigned short));
    unsigned short* Xb  = (unsigned short*)alloc((size_t)N_NODES_C * DIM * sizeof(unsigned short));
    unsigned short* Hb1 = (unsigned short*)alloc((size_t)N_NODES_C * DIM * sizeof(unsigned short));
    unsigned short* Hb2 = (unsigned short*)alloc((size_t)N_NODES_C * DIM * sizeof(unsigned short));
    unsigned short* Wb  = (unsigned short*)alloc((size_t)4 * DIM * DIM * sizeof(unsigned short));

    hipMemsetAsync(deg, 0, N_NODES_C * sizeof(int), stream);

    k_pre<<<F2B_NB + 64 + 4, 256, 0, stream>>>(X, W0, W1, W2, W3, Xb, Wb, scale_inv);
    k_deg<<<(N_EDGES_C + 255) / 256, 256, 0, stream>>>(A, deg, N_EDGES_C);
    k_scan_part<<<SCAN_NB, 256, 0, stream>>>(deg, part, dinv, fill, N_NODES_C);
    k_scan_final<<<SCAN_NB, 256, 0, stream>>>(deg, part, ptr, N_NODES_C, SCAN_NB);
    k_fill<<<(N_EDGES_C + 255) / 256, 256, 0, stream>>>(A, ptr, fill, esrc, N_EDGES_C);

    const int gemm_grid = (N_NODES_C + 63) / 64;
    const int agg_grid  = (N_NODES_C + 7) / 8;

    // layer 0
    k_gemm_mfma<<<gemm_grid, 256, 0, stream>>>(Xb, Wb + 0 * DIM * DIM, scale_inv + 0, dinv, Gb, N_NODES_C);
    k_agg<<<agg_grid, 256, 0, stream>>>(Gb, b0, dinv, ptr, esrc, nullptr, Hb1, 0, N_NODES_C);
    // layer 1
    k_gemm_mfma<<<gemm_grid, 256, 0, stream>>>(Hb1, Wb + 1 * DIM * DIM, scale_inv + 1, dinv, Gb, N_NODES_C);
    k_agg<<<agg_grid, 256, 0, stream>>>(Gb, b1, dinv, ptr, esrc, Hb1, Hb2, 1, N_NODES_C);
    // layer 2
    k_gemm_mfma<<<gemm_grid, 256, 0, stream>>>(Hb2, Wb + 2 * DIM * DIM, scale_inv + 2, dinv, Gb, N_NODES_C);
    k_agg<<<agg_grid, 256, 0, stream>>>(Gb, b2, dinv, ptr, esrc, Hb2, Hb1, 1, N_NODES_C);
    // layer 3
    k_gemm_mfma<<<gemm_grid, 256, 0, stream>>>(Hb1, Wb + 3 * DIM * DIM, scale_inv + 3, dinv, Gb, N_NODES_C);
    k_agg<<<agg_grid, 256, 0, stream>>>(Gb, b3, dinv, ptr, esrc, Hb1, Hb2, 1, N_NODES_C);
    // final classifier
    k_final<<<(N_NODES_C + 63) / 64, 256, 0, stream>>>(Hb2, Wf, bf, out, N_NODES_C);
}